// Round 1
// baseline (1702.105 us; speedup 1.0000x reference)
//
#include <hip/hip_runtime.h>
#include <stdint.h>

#define FD   256
#define NA   8649
#define LSTR 8704
#define PB   (33*33*FD)   // per-batch padded integral-image plane (f fastest)
#define TA   16

// ---------------- integral images (P[b][i][j][f], 33x33 padded) ----------------
__global__ __launch_bounds__(256) void k_rowsum(const float* __restrict__ kin,
    const float* __restrict__ vin, float* __restrict__ Pk,
    float* __restrict__ Pk2, float* __restrict__ Pv) {
  int b = blockIdx.x >> 5, i = blockIdx.x & 31;
  int f = threadIdx.x;
  const float* kr = kin + ((size_t)b*1024 + i*32)*FD + f;
  const float* vr = vin + ((size_t)b*1024 + i*32)*FD + f;
  float sk = 0.f, sk2 = 0.f, sv = 0.f;
  size_t base = (size_t)b*PB + (size_t)(i+1)*33*FD + f;
  #pragma unroll
  for (int j = 0; j < 32; ++j) {
    float kv = kr[j*FD], vv = vr[j*FD];
    sk += kv; sk2 += kv*kv; sv += vv;
    size_t p = base + (size_t)(j+1)*FD;
    Pk[p] = sk; Pk2[p] = sk2; Pv[p] = sv;
  }
}

__global__ __launch_bounds__(256) void k_colsum(float* __restrict__ Pk,
    float* __restrict__ Pk2, float* __restrict__ Pv) {
  int j = blockIdx.x, b = blockIdx.y, f = threadIdx.x;
  size_t base = (size_t)b*PB + f;
  if (j == 0) {
    for (int i = 0; i < 33; ++i) {
      size_t p = base + (size_t)i*33*FD;
      Pk[p] = 0.f; Pk2[p] = 0.f; Pv[p] = 0.f;
    }
  } else {
    size_t p0 = base + (size_t)j*FD;
    Pk[p0] = 0.f; Pk2[p0] = 0.f; Pv[p0] = 0.f;
    float ak = 0.f, ak2 = 0.f, av = 0.f;
    for (int i = 1; i <= 32; ++i) {
      size_t p = base + ((size_t)i*33 + j)*FD;
      ak  += Pk[p];  Pk[p]  = ak;
      ak2 += Pk2[p]; Pk2[p] = ak2;
      av  += Pv[p];  Pv[p]  = av;
    }
  }
}

// ---------------- area table: pack (r,c,ah,aw) ----------------
__global__ __launch_bounds__(256) void k_tab(uint32_t* __restrict__ tab) {
  int a = blockIdx.x*256 + threadIdx.x;
  if (a >= NA) return;
  const int offs[10] = {0,1024,2016,2976,3968,4929,5859,6819,7749,8649};
  int s = 0;
  #pragma unroll
  for (int i = 1; i < 9; ++i) s += (a >= offs[i]) ? 1 : 0;
  int ah = s/3, aw = s - ah*3;
  int idx = a - offs[s];
  int wc = 32 - aw;
  int r = idx / wc;
  int c = idx - r*wc;
  tab[a] = (uint32_t)(r | (c<<6) | (ah<<12) | (aw<<14));
}

// ---------------- fold size_embed@W1[512:768] + b1 into 9 bias vectors ----------------
__global__ __launch_bounds__(256) void k_bias9(const float* __restrict__ eh,
    const float* __restrict__ ew, const float* __restrict__ W1,
    const float* __restrict__ b1, float* __restrict__ bias9) {
  int s = blockIdx.x, c = threadIdx.x;
  int ah = s/3, aw = s - ah*3;
  float acc = b1[c];
  for (int j = 0; j < 128; ++j) acc += eh[ah*128 + j] * W1[(size_t)(512+j)*FD + c];
  for (int j = 0; j < 128; ++j) acc += ew[aw*128 + j] * W1[(size_t)(640+j)*FD + c];
  bias9[s*FD + c] = acc;
}

// ---------------- fused MLP: k_area = relu([mean,std]@W1'+bias9)@W2+b2 ----------------
__global__ __launch_bounds__(256) void k_mlp(
    const float* __restrict__ Pk, const float* __restrict__ Pk2,
    const uint32_t* __restrict__ tab, const float* __restrict__ W1,
    const float* __restrict__ W2, const float* __restrict__ b2,
    const float* __restrict__ bias9, float* __restrict__ karea) {
  __shared__ __align__(16) float Xs[TA*513];   // [a][k], k in 0..511 (mean|std); aliased as Hs[a][257] later
  __shared__ __align__(16) float Wt[32*FD];    // streamed weight chunk
  __shared__ int segs[TA];
  int t = threadIdx.x;
  int b = blockIdx.y;
  int a0 = blockIdx.x * TA;
  int tx = t & 63, ty = t >> 6;                // cols 4*tx..4*tx+3, areas 4*ty..4*ty+3
  const float* Pkb  = Pk  + (size_t)b*PB;
  const float* Pk2b = Pk2 + (size_t)b*PB;
  {
    int f = t;
    for (int al = 0; al < TA; ++al) {
      int a = a0 + al; int aa = (a < NA) ? a : (NA-1);
      uint32_t tb = tab[aa];
      int r1 = tb & 63, c1 = (tb>>6)&63, ah = (tb>>12)&3, aw = (tb>>14)&3;
      int r2 = r1+ah+1, c2 = c1+aw+1;
      int i11 = (r1*33+c1)*FD+f, i12 = (r1*33+c2)*FD+f;
      int i21 = (r2*33+c1)*FD+f, i22 = (r2*33+c2)*FD+f;
      float s  = Pkb[i22]  - Pkb[i12]  - Pkb[i21]  + Pkb[i11];
      float s2 = Pk2b[i22] - Pk2b[i12] - Pk2b[i21] + Pk2b[i11];
      float inv = 1.0f / (float)((ah+1)*(aw+1));
      float mean = s * inv;
      float var = s2 * inv - mean*mean;
      float sd = sqrtf(fabsf(var) + 1e-6f);
      Xs[al*513 + f]       = mean;
      Xs[al*513 + 256 + f] = sd;
      if (t == 0) segs[al] = ah*3 + aw;
    }
  }
  float acc[4][4];
  #pragma unroll
  for (int i = 0; i < 4; ++i)
    #pragma unroll
    for (int j = 0; j < 4; ++j) acc[i][j] = 0.f;
  for (int kc = 0; kc < 512; kc += 32) {
    __syncthreads();
    for (int l = t; l < 32*FD; l += 256) Wt[l] = W1[(size_t)kc*FD + l];
    __syncthreads();
    #pragma unroll
    for (int kk = 0; kk < 32; ++kk) {
      float xv[4];
      #pragma unroll
      for (int ia = 0; ia < 4; ++ia) xv[ia] = Xs[(4*ty+ia)*513 + kc + kk];
      float4 w = *(const float4*)&Wt[kk*FD + 4*tx];
      float wv[4] = {w.x, w.y, w.z, w.w};
      #pragma unroll
      for (int ia = 0; ia < 4; ++ia)
        #pragma unroll
        for (int ic = 0; ic < 4; ++ic) acc[ia][ic] += xv[ia] * wv[ic];
    }
  }
  __syncthreads();
  float* Hs = Xs;                               // reuse X region: [a][257]
  #pragma unroll
  for (int ia = 0; ia < 4; ++ia) {
    int al = 4*ty + ia;
    const float* bseg = bias9 + segs[al]*FD;
    #pragma unroll
    for (int ic = 0; ic < 4; ++ic) {
      int c = 4*tx + ic;
      Hs[al*257 + c] = fmaxf(acc[ia][ic] + bseg[c], 0.f);
    }
  }
  float acc2[4][4];
  #pragma unroll
  for (int i = 0; i < 4; ++i)
    #pragma unroll
    for (int j = 0; j < 4; ++j) acc2[i][j] = 0.f;
  for (int kc = 0; kc < 256; kc += 32) {
    __syncthreads();
    for (int l = t; l < 32*FD; l += 256) Wt[l] = W2[(size_t)kc*FD + l];
    __syncthreads();
    #pragma unroll
    for (int kk = 0; kk < 32; ++kk) {
      float hv[4];
      #pragma unroll
      for (int ia = 0; ia < 4; ++ia) hv[ia] = Hs[(4*ty+ia)*257 + kc + kk];
      float4 w = *(const float4*)&Wt[kk*FD + 4*tx];
      float wv[4] = {w.x, w.y, w.z, w.w};
      #pragma unroll
      for (int ia = 0; ia < 4; ++ia)
        #pragma unroll
        for (int ic = 0; ic < 4; ++ic) acc2[ia][ic] += hv[ia] * wv[ic];
    }
  }
  float4 bb = *(const float4*)&b2[4*tx];
  #pragma unroll
  for (int ia = 0; ia < 4; ++ia) {
    int a = a0 + 4*ty + ia;
    if (a < NA) {
      float4 o;
      o.x = acc2[ia][0] + bb.x; o.y = acc2[ia][1] + bb.y;
      o.z = acc2[ia][2] + bb.z; o.w = acc2[ia][3] + bb.w;
      *(float4*)&karea[((size_t)b*NA + a)*FD + 4*tx] = o;
    }
  }
}

// ---------------- v_area from P_v ----------------
__global__ __launch_bounds__(256) void k_varea(const float* __restrict__ Pv,
    const uint32_t* __restrict__ tab, float* __restrict__ varea) {
  int a = blockIdx.x, f = threadIdx.x;
  uint32_t tb = tab[a];
  int r1 = tb & 63, c1 = (tb>>6)&63, ah = (tb>>12)&3, aw = (tb>>14)&3;
  int r2 = r1+ah+1, c2 = c1+aw+1;
  int i11 = (r1*33+c1)*FD+f, i12 = (r1*33+c2)*FD+f;
  int i21 = (r2*33+c1)*FD+f, i22 = (r2*33+c2)*FD+f;
  for (int b = 0; b < 8; ++b) {
    const float* Pb = Pv + (size_t)b*PB;
    varea[((size_t)b*NA + a)*FD + f] = Pb[i22] - Pb[i12] - Pb[i21] + Pb[i11];
  }
}

// ---------------- logits GEMM (per b): 128x128 tile, 8x8 micro ----------------
__global__ __launch_bounds__(256) void k_logits(const float* __restrict__ qm,
    const float* __restrict__ karea, float* __restrict__ logits, int b) {
  __shared__ __align__(16) float Qs[32*132];
  __shared__ __align__(16) float Ks[32*132];
  int t = threadIdx.x;
  int m0 = blockIdx.x * 128;
  int a0 = blockIdx.y * 128;
  int tx = t & 15, ty = t >> 4;
  const float* qb = qm + (size_t)b*1024*FD;
  const float* kb = karea + (size_t)b*NA*FD;
  float acc[8][8];
  #pragma unroll
  for (int i = 0; i < 8; ++i)
    #pragma unroll
    for (int j = 0; j < 8; ++j) acc[i][j] = 0.f;
  for (int kc = 0; kc < 256; kc += 32) {
    for (int l = t; l < 4096; l += 256) {
      int row = l >> 5, kk = l & 31;
      Qs[kk*132 + row] = qb[(size_t)(m0+row)*FD + kc + kk];
      int a = a0 + row; int aa = (a < NA) ? a : (NA-1);
      Ks[kk*132 + row] = kb[(size_t)aa*FD + kc + kk];
    }
    __syncthreads();
    #pragma unroll
    for (int kk = 0; kk < 32; ++kk) {
      float4 q0 = *(const float4*)&Qs[kk*132 + 8*ty];
      float4 q1 = *(const float4*)&Qs[kk*132 + 8*ty + 4];
      float4 k0 = *(const float4*)&Ks[kk*132 + 8*tx];
      float4 k1 = *(const float4*)&Ks[kk*132 + 8*tx + 4];
      float qf[8] = {q0.x,q0.y,q0.z,q0.w,q1.x,q1.y,q1.z,q1.w};
      float kf[8] = {k0.x,k0.y,k0.z,k0.w,k1.x,k1.y,k1.z,k1.w};
      #pragma unroll
      for (int i = 0; i < 8; ++i)
        #pragma unroll
        for (int j = 0; j < 8; ++j) acc[i][j] += qf[i] * kf[j];
    }
    __syncthreads();
  }
  #pragma unroll
  for (int i = 0; i < 8; ++i) {
    float* dst = logits + (size_t)(m0 + 8*ty + i)*LSTR + a0 + 8*tx;
    float4 s0, s1;
    s0.x = acc[i][0]; s0.y = acc[i][1]; s0.z = acc[i][2]; s0.w = acc[i][3];
    s1.x = acc[i][4]; s1.y = acc[i][5]; s1.z = acc[i][6]; s1.w = acc[i][7];
    *(float4*)&dst[0] = s0;            // pad columns >= NA are never read
    *(float4*)&dst[4] = s1;
  }
}

// ---------------- softmax + exact top-64 threshold + weighted v_area sum ----------------
__device__ __forceinline__ uint32_t f2key(float x) {
  uint32_t u = __float_as_uint(x);
  return (u & 0x80000000u) ? ~u : (u | 0x80000000u);
}

__global__ __launch_bounds__(256) void k_final(const float* __restrict__ logits,
    const float* __restrict__ varea, float* __restrict__ outp, int b) {
  __shared__ float L[NA];
  __shared__ float red[4];
  __shared__ int   redi[4];
  __shared__ int   lst[192];
  __shared__ float lw[192];
  __shared__ int   shcnt;
  int t = threadIdx.x;
  int qrow = blockIdx.x;
  const float* row = logits + (size_t)qrow*LSTR;

  uint32_t keys[34];
  float vmax = -__builtin_inff();
  #pragma unroll
  for (int i = 0; i < 34; ++i) {
    int idx = t + i*256;
    float x = (idx < NA) ? row[idx] : -__builtin_inff();
    if (idx < NA) L[idx] = x;
    keys[i] = f2key(x);
    vmax = fmaxf(vmax, x);
  }
  #pragma unroll
  for (int off = 32; off >= 1; off >>= 1) vmax = fmaxf(vmax, __shfl_xor(vmax, off));
  if ((t & 63) == 0) red[t >> 6] = vmax;
  __syncthreads();
  float maxv = fmaxf(fmaxf(red[0], red[1]), fmaxf(red[2], red[3]));

  // bisection for exact 64th-largest logit key
  uint32_t lo = 0u, hi = 0xFFFFFFFFu;
  for (int it = 0; it < 32; ++it) {
    uint32_t mid = (uint32_t)((((uint64_t)lo + (uint64_t)hi) + 1ull) >> 1);
    int c = 0;
    #pragma unroll
    for (int i = 0; i < 34; ++i) c += (keys[i] >= mid) ? 1 : 0;
    #pragma unroll
    for (int off = 32; off >= 1; off >>= 1) c += __shfl_xor(c, off);
    if ((t & 63) == 0) redi[t >> 6] = c;
    __syncthreads();
    int ctot = redi[0] + redi[1] + redi[2] + redi[3];
    __syncthreads();
    if (ctot >= 64) lo = mid; else hi = mid - 1;
  }
  uint32_t thr = lo;

  if (t == 0) shcnt = 0;
  __syncthreads();
  #pragma unroll
  for (int i = 0; i < 34; ++i) {
    int idx = t + i*256;
    if (idx < NA && keys[i] >= thr) {
      int p = atomicAdd(&shcnt, 1);
      if (p < 192) lst[p] = idx;
    }
  }
  __syncthreads();
  int S = min(shcnt, 192);
  for (int i = t; i < S; i += 256) lw[i] = expf(L[lst[i]] - maxv);
  __syncthreads();
  float ssum = 0.f;
  if (t < 64) {
    for (int i = t; i < S; i += 64) ssum += lw[i];
    #pragma unroll
    for (int off = 32; off >= 1; off >>= 1) ssum += __shfl_xor(ssum, off);
    if (t == 0) red[0] = ssum;
  }
  __syncthreads();
  float inv = 1.0f / red[0];
  const float* vb = varea + (size_t)b*NA*FD;
  float acc = 0.f;
  for (int i = 0; i < S; ++i) acc += lw[i] * vb[(size_t)lst[i]*FD + t];
  outp[((size_t)b*1024 + qrow)*FD + t] = acc * inv;
}

extern "C" void kernel_launch(void* const* d_in, const int* in_sizes, int n_in,
                              void* d_out, int out_size, void* d_ws, size_t ws_size,
                              hipStream_t stream) {
  const float* q  = (const float*)d_in[0];
  const float* k  = (const float*)d_in[1];
  const float* v  = (const float*)d_in[2];
  const float* eh = (const float*)d_in[3];
  const float* ew = (const float*)d_in[4];
  const float* W1 = (const float*)d_in[5];
  const float* b1 = (const float*)d_in[6];
  const float* W2 = (const float*)d_in[7];
  const float* b2 = (const float*)d_in[8];
  float* out = (float*)d_out;
  float* ws  = (float*)d_ws;

  size_t off = 0;
  float* Pk    = ws + off; off += (size_t)8*PB;
  float* Pk2   = ws + off; off += (size_t)8*PB;
  float* Pv    = ws + off; off += (size_t)8*PB;
  float* karea = ws + off; off += (size_t)8*NA*FD;
  float* varea = ws + off; off += (size_t)8*NA*FD;
  float* bias9 = ws + off; off += 9*FD;
  uint32_t* tab = (uint32_t*)(ws + off); off += 8704;
  float* logits = ws + off; off += (size_t)1024*LSTR;   // per-b reuse; total ws ~204 MB

  k_rowsum<<<dim3(256), dim3(256), 0, stream>>>(k, v, Pk, Pk2, Pv);
  k_colsum<<<dim3(33, 8), dim3(256), 0, stream>>>(Pk, Pk2, Pv);
  k_tab<<<dim3(34), dim3(256), 0, stream>>>(tab);
  k_bias9<<<dim3(9), dim3(256), 0, stream>>>(eh, ew, W1, b1, bias9);
  k_mlp<<<dim3(541, 8), dim3(256), 0, stream>>>(Pk, Pk2, tab, W1, W2, b2, bias9, karea);
  k_varea<<<dim3(NA), dim3(256), 0, stream>>>(Pv, tab, varea);
  for (int b = 0; b < 8; ++b) {
    k_logits<<<dim3(8, 68), dim3(256), 0, stream>>>(q, karea, logits, b);
    k_final<<<dim3(1024), dim3(256), 0, stream>>>(logits, varea, out, b);
  }
}

// Round 2
// 1293.116 us; speedup vs baseline: 1.3163x; 1.3163x over previous
//
#include <hip/hip_runtime.h>
#include <stdint.h>

#define FD   256
#define NA   8649
#define MT   69192          // 8*NA flattened rows
#define LSTR 8704
#define PB   (33*33*FD)

typedef unsigned short ushort_t;
typedef short bf16x8 __attribute__((ext_vector_type(8)));
typedef float f32x4  __attribute__((ext_vector_type(4)));

// ---------- bf16 split helpers ----------
__device__ __forceinline__ unsigned short f2bf(float x) {
  unsigned int u = __float_as_uint(x);
  unsigned int r = (u + 0x7FFFu + ((u >> 16) & 1u)) >> 16;
  return (unsigned short)r;
}
__device__ __forceinline__ float bf2f(unsigned short h) {
  return __uint_as_float(((unsigned int)h) << 16);
}
__device__ __forceinline__ void dec2(float x, unsigned short& h, unsigned short& l) {
  h = f2bf(x);
  l = f2bf(x - bf2f(h));
}

// ---------- global->LDS direct (width 16), wave-uniform dst ----------
__device__ __forceinline__ void gl2lds(const void* g, void* l) {
  __builtin_amdgcn_global_load_lds(
      (const __attribute__((address_space(1))) void*)g,
      (__attribute__((address_space(3))) void*)l, 16, 0, 0);
}

// ---------- LDS fragment read: tile row-major [R][64] bf16, chunk-XOR swizzle ----------
__device__ __forceinline__ bf16x8 fld(const ushort_t* base, int row, int q) {
  return *(const bf16x8*)(base + row*64 + ((q ^ (row & 7)) << 3));
}

// ---------- 3-term split MFMA ----------
__device__ __forceinline__ f32x4 mfma3(bf16x8 ah, bf16x8 al, bf16x8 bh, bf16x8 bl, f32x4 acc) {
  acc = __builtin_amdgcn_mfma_f32_16x16x32_bf16(al, bh, acc, 0, 0, 0);
  acc = __builtin_amdgcn_mfma_f32_16x16x32_bf16(ah, bl, acc, 0, 0, 0);
  acc = __builtin_amdgcn_mfma_f32_16x16x32_bf16(ah, bh, acc, 0, 0, 0);
  return acc;
}

// ================= integral images =================
__global__ __launch_bounds__(256) void k_rowsum(const float* __restrict__ kin,
    const float* __restrict__ vin, float* __restrict__ Pk,
    float* __restrict__ Pk2, float* __restrict__ Pv) {
  int b = blockIdx.x >> 5, i = blockIdx.x & 31;
  int f = threadIdx.x;
  const float* kr = kin + ((size_t)b*1024 + i*32)*FD + f;
  const float* vr = vin + ((size_t)b*1024 + i*32)*FD + f;
  float sk = 0.f, sk2 = 0.f, sv = 0.f;
  size_t base = (size_t)b*PB + (size_t)(i+1)*33*FD + f;
  #pragma unroll
  for (int j = 0; j < 32; ++j) {
    float kv = kr[j*FD], vv = vr[j*FD];
    sk += kv; sk2 += kv*kv; sv += vv;
    size_t p = base + (size_t)(j+1)*FD;
    Pk[p] = sk; Pk2[p] = sk2; Pv[p] = sv;
  }
}

__global__ __launch_bounds__(256) void k_colsum(float* __restrict__ Pk,
    float* __restrict__ Pk2, float* __restrict__ Pv) {
  int j = blockIdx.x, b = blockIdx.y, f = threadIdx.x;
  size_t base = (size_t)b*PB + f;
  if (j == 0) {
    for (int i = 0; i < 33; ++i) {
      size_t p = base + (size_t)i*33*FD;
      Pk[p] = 0.f; Pk2[p] = 0.f; Pv[p] = 0.f;
    }
  } else {
    size_t p0 = base + (size_t)j*FD;
    Pk[p0] = 0.f; Pk2[p0] = 0.f; Pv[p0] = 0.f;
    float ak = 0.f, ak2 = 0.f, av = 0.f;
    for (int i = 1; i <= 32; ++i) {
      size_t p = base + ((size_t)i*33 + j)*FD;
      ak  += Pk[p];  Pk[p]  = ak;
      ak2 += Pk2[p]; Pk2[p] = ak2;
      av  += Pv[p];  Pv[p]  = av;
    }
  }
}

// ================= area table =================
__global__ __launch_bounds__(256) void k_tab(uint32_t* __restrict__ tab) {
  int a = blockIdx.x*256 + threadIdx.x;
  if (a >= NA) return;
  const int offs[10] = {0,1024,2016,2976,3968,4929,5859,6819,7749,8649};
  int s = 0;
  #pragma unroll
  for (int i = 1; i < 9; ++i) s += (a >= offs[i]) ? 1 : 0;
  int ah = s/3, aw = s - ah*3;
  int idx = a - offs[s];
  int wc = 32 - aw;
  int r = idx / wc;
  int c = idx - r*wc;
  tab[a] = (uint32_t)(r | (c<<6) | (ah<<12) | (aw<<14));
}

// ================= fold size-embed into 9 bias vectors =================
__global__ __launch_bounds__(256) void k_bias9(const float* __restrict__ eh,
    const float* __restrict__ ew, const float* __restrict__ W1,
    const float* __restrict__ b1, float* __restrict__ bias9) {
  int s = blockIdx.x, c = threadIdx.x;
  int ah = s/3, aw = s - ah*3;
  float acc = b1[c];
  for (int j = 0; j < 128; ++j) acc += eh[ah*128 + j] * W1[(size_t)(512+j)*FD + c];
  for (int j = 0; j < 128; ++j) acc += ew[aw*128 + j] * W1[(size_t)(640+j)*FD + c];
  bias9[s*FD + c] = acc;
}

// ================= decompose q into hi/lo bf16 =================
__global__ __launch_bounds__(256) void k_decompq(const float* __restrict__ q,
    ushort_t* __restrict__ qh, ushort_t* __restrict__ ql) {
  int i = (blockIdx.x*256 + threadIdx.x) * 8;   // 8*1024*256 total
  float4 v0 = *(const float4*)(q + i);
  float4 v1 = *(const float4*)(q + i + 4);
  float e[8] = {v0.x, v0.y, v0.z, v0.w, v1.x, v1.y, v1.z, v1.w};
  bf16x8 h8, l8;
  #pragma unroll
  for (int j = 0; j < 8; ++j) {
    unsigned short hu, lu; dec2(e[j], hu, lu);
    h8[j] = (short)hu; l8[j] = (short)lu;
  }
  *(bf16x8*)(qh + i) = h8;
  *(bf16x8*)(ql + i) = l8;
}

// ================= decompose+transpose W1, W2 -> [n][k] hi/lo =================
__global__ __launch_bounds__(256) void k_decompw(const float* __restrict__ W1,
    const float* __restrict__ W2, ushort_t* __restrict__ w1h, ushort_t* __restrict__ w1l,
    ushort_t* __restrict__ w2h, ushort_t* __restrict__ w2l) {
  int e = blockIdx.x*256 + threadIdx.x;   // 196608 total
  float x; unsigned short hu, lu;
  if (e < 131072) {
    int n = e >> 9, kk = e & 511;
    x = W1[(size_t)kk*FD + n];
    dec2(x, hu, lu);
    w1h[e] = hu; w1l[e] = lu;
  } else {
    int e2 = e - 131072;
    int n = e2 >> 8, kk = e2 & 255;
    x = W2[(size_t)kk*FD + n];
    dec2(x, hu, lu);
    w2h[e2] = hu; w2l[e2] = lu;
  }
}

// ================= MLP layer 1 (fused area-feature compute) =================
// BM=128 rows (flattened b*NA+a), BN=256, K=512 (BK=64), 512 thr / 8 waves (2x4)
__global__ __launch_bounds__(512) void k_l1(
    const float* __restrict__ Pk, const float* __restrict__ Pk2,
    const uint32_t* __restrict__ tab, const ushort_t* __restrict__ w1h,
    const ushort_t* __restrict__ w1l, const float* __restrict__ bias9g,
    ushort_t* __restrict__ hh, ushort_t* __restrict__ hl) {
  __shared__ ushort_t AsH[128*64], AsL[128*64];
  __shared__ ushort_t BsH[256*64], BsL[256*64];
  __shared__ float bias9s[9*256];
  __shared__ uint32_t mc11[128], mc12[128], mc21[128], mc22[128], mpof[128];
  __shared__ float minv[128];
  __shared__ int   mseg[128];

  int t = threadIdx.x, lane = t & 63, wid = t >> 6;
  int wr = wid >> 2, wc = wid & 3;
  size_t row0 = (size_t)blockIdx.x * 128;

  if (t < 128) {
    size_t gr = row0 + t;
    uint32_t c11=0,c12=0,c21=0,c22=0,pof=0; float inv=0.f; int seg=0;
    if (gr < MT) {
      int bi = (int)(gr / NA);
      int a  = (int)(gr - (size_t)bi*NA);
      uint32_t tb = tab[a];
      int r1 = tb & 63, c1 = (tb>>6)&63, ah=(tb>>12)&3, aw=(tb>>14)&3;
      int r2 = r1+ah+1, c2 = c1+aw+1;
      c11 = (uint32_t)((r1*33+c1)*FD); c12 = (uint32_t)((r1*33+c2)*FD);
      c21 = (uint32_t)((r2*33+c1)*FD); c22 = (uint32_t)((r2*33+c2)*FD);
      pof = (uint32_t)(bi*PB);
      inv = 1.0f/(float)((ah+1)*(aw+1));
      seg = ah*3+aw;
    }
    mc11[t]=c11; mc12[t]=c12; mc21[t]=c21; mc22[t]=c22;
    mpof[t]=pof; minv[t]=inv; mseg[t]=seg;
  }
  for (int i = t; i < 9*256; i += 512) bias9s[i] = bias9g[i];
  __syncthreads();

  f32x4 acc[4][4];
  #pragma unroll
  for (int i = 0; i < 4; ++i)
    #pragma unroll
    for (int j = 0; j < 4; ++j) acc[i][j] = (f32x4)0.f;

  for (int kc = 0; kc < 512; kc += 64) {
    // ---- A: compute X chunk (mean or std) and write swizzled to LDS ----
    {
      int lr = t >> 2, fb = t & 3;
      const float* PKb  = Pk  + mpof[lr];
      const float* PK2b = Pk2 + mpof[lr];
      uint32_t c11=mc11[lr], c12=mc12[lr], c21=mc21[lr], c22=mc22[lr];
      float inv = minv[lr];
      bool is_std = (kc >= 256);
      int f0 = (kc & 255) + fb*16;
      #pragma unroll
      for (int cc = 0; cc < 2; ++cc) {
        bf16x8 vh, vl;
        #pragma unroll
        for (int j = 0; j < 8; ++j) {
          int f = f0 + cc*8 + j;
          float s = PKb[c22+f] - PKb[c12+f] - PKb[c21+f] + PKb[c11+f];
          float x;
          if (!is_std) {
            x = s * inv;
          } else {
            float s2 = PK2b[c22+f] - PK2b[c12+f] - PK2b[c21+f] + PK2b[c11+f];
            float mn = s * inv;
            x = sqrtf(fabsf(s2*inv - mn*mn) + 1e-6f);
          }
          unsigned short hu, lu; dec2(x, hu, lu);
          vh[j] = (short)hu; vl[j] = (short)lu;
        }
        int cl = fb*2 + cc;
        int slot = (cl ^ (lr & 7)) << 3;
        *(bf16x8*)(AsH + lr*64 + slot) = vh;
        *(bf16x8*)(AsL + lr*64 + slot) = vl;
      }
    }
    // ---- B: stage W1t tile [256][64] hi/lo via global_load_lds ----
    #pragma unroll
    for (int i = 0; i < 4; ++i) {
      int r0 = (wid + 8*i) * 8;
      int lr = r0 + (lane >> 3);
      int lc = (lane & 7) ^ (lr & 7);
      gl2lds(w1h + (size_t)lr*512 + kc + lc*8, BsH + r0*64);
      gl2lds(w1l + (size_t)lr*512 + kc + lc*8, BsL + r0*64);
    }
    __syncthreads();
    // ---- MFMA ----
    #pragma unroll
    for (int w = 0; w < 2; ++w) {
      int qq = w*4 + (lane >> 4);
      bf16x8 ah[4], al[4], bh[4], bl[4];
      #pragma unroll
      for (int i = 0; i < 4; ++i) {
        int ra = wr*64 + i*16 + (lane & 15);
        ah[i] = fld(AsH, ra, qq); al[i] = fld(AsL, ra, qq);
        int rb = wc*64 + i*16 + (lane & 15);
        bh[i] = fld(BsH, rb, qq); bl[i] = fld(BsL, rb, qq);
      }
      #pragma unroll
      for (int mt = 0; mt < 4; ++mt)
        #pragma unroll
        for (int nt = 0; nt < 4; ++nt)
          acc[mt][nt] = mfma3(ah[mt], al[mt], bh[nt], bl[nt], acc[mt][nt]);
    }
    __syncthreads();
  }

  // ---- epilogue: h = relu(acc + bias9[seg]) -> hi/lo bf16 ----
  #pragma unroll
  for (int mt = 0; mt < 4; ++mt) {
    int lrow0 = wr*64 + mt*16 + (lane >> 4)*4;
    #pragma unroll
    for (int nt = 0; nt < 4; ++nt) {
      int col = wc*64 + nt*16 + (lane & 15);
      #pragma unroll
      for (int r = 0; r < 4; ++r) {
        int lrow = lrow0 + r;
        size_t gr = row0 + lrow;
        if (gr < MT) {
          float hv = fmaxf(acc[mt][nt][r] + bias9s[mseg[lrow]*FD + col], 0.f);
          unsigned short hu, lu; dec2(hv, hu, lu);
          hh[gr*FD + col] = hu;
          hl[gr*FD + col] = lu;
        }
      }
    }
  }
}

// ================= MLP layer 2 =================
// BM=128, BN=256, K=256 (BK=64), 512 thr / 8 waves
__global__ __launch_bounds__(512) void k_l2(
    const ushort_t* __restrict__ hh, const ushort_t* __restrict__ hl,
    const ushort_t* __restrict__ w2h, const ushort_t* __restrict__ w2l,
    const float* __restrict__ b2,
    ushort_t* __restrict__ kh, ushort_t* __restrict__ kl) {
  __shared__ ushort_t AsH[128*64], AsL[128*64];
  __shared__ ushort_t BsH[256*64], BsL[256*64];
  __shared__ float b2s[256];

  int t = threadIdx.x, lane = t & 63, wid = t >> 6;
  int wr = wid >> 2, wc = wid & 3;
  size_t row0 = (size_t)blockIdx.x * 128;
  if (t < 256) b2s[t] = b2[t];

  f32x4 acc[4][4];
  #pragma unroll
  for (int i = 0; i < 4; ++i)
    #pragma unroll
    for (int j = 0; j < 4; ++j) acc[i][j] = (f32x4)0.f;

  for (int kc = 0; kc < 256; kc += 64) {
    #pragma unroll
    for (int i = 0; i < 2; ++i) {
      int r0 = (wid + 8*i) * 8;
      int lr = r0 + (lane >> 3);
      int lc = (lane & 7) ^ (lr & 7);
      size_t gr = row0 + lr; if (gr > MT-1) gr = MT-1;
      gl2lds(hh + gr*FD + kc + lc*8, AsH + r0*64);
      gl2lds(hl + gr*FD + kc + lc*8, AsL + r0*64);
    }
    #pragma unroll
    for (int i = 0; i < 4; ++i) {
      int r0 = (wid + 8*i) * 8;
      int lr = r0 + (lane >> 3);
      int lc = (lane & 7) ^ (lr & 7);
      gl2lds(w2h + (size_t)lr*FD + kc + lc*8, BsH + r0*64);
      gl2lds(w2l + (size_t)lr*FD + kc + lc*8, BsL + r0*64);
    }
    __syncthreads();
    #pragma unroll
    for (int w = 0; w < 2; ++w) {
      int qq = w*4 + (lane >> 4);
      bf16x8 ah[4], al[4], bh[4], bl[4];
      #pragma unroll
      for (int i = 0; i < 4; ++i) {
        int ra = wr*64 + i*16 + (lane & 15);
        ah[i] = fld(AsH, ra, qq); al[i] = fld(AsL, ra, qq);
        int rb = wc*64 + i*16 + (lane & 15);
        bh[i] = fld(BsH, rb, qq); bl[i] = fld(BsL, rb, qq);
      }
      #pragma unroll
      for (int mt = 0; mt < 4; ++mt)
        #pragma unroll
        for (int nt = 0; nt < 4; ++nt)
          acc[mt][nt] = mfma3(ah[mt], al[mt], bh[nt], bl[nt], acc[mt][nt]);
    }
    __syncthreads();
  }

  #pragma unroll
  for (int mt = 0; mt < 4; ++mt) {
    int lrow0 = wr*64 + mt*16 + (lane >> 4)*4;
    #pragma unroll
    for (int nt = 0; nt < 4; ++nt) {
      int col = wc*64 + nt*16 + (lane & 15);
      #pragma unroll
      for (int r = 0; r < 4; ++r) {
        size_t gr = row0 + lrow0 + r;
        if (gr < MT) {
          float kv = acc[mt][nt][r] + b2s[col];
          unsigned short hu, lu; dec2(kv, hu, lu);
          kh[gr*FD + col] = hu;
          kl[gr*FD + col] = lu;
        }
      }
    }
  }
}

// ================= logits GEMM: q @ karea^T (per b) =================
// BM=128, BN=128, K=256 (BK=64), 256 thr / 4 waves (2x2)
__global__ __launch_bounds__(256) void k_logits(
    const ushort_t* __restrict__ qh, const ushort_t* __restrict__ ql,
    const ushort_t* __restrict__ kh, const ushort_t* __restrict__ kl,
    float* __restrict__ logits, int b) {
  __shared__ ushort_t AsH[128*64], AsL[128*64];
  __shared__ ushort_t BsH[128*64], BsL[128*64];

  int t = threadIdx.x, lane = t & 63, wid = t >> 6;
  int wr = wid >> 1, wc = wid & 1;
  int m0 = blockIdx.x * 128;
  int a0 = blockIdx.y * 128;
  size_t qbase = (size_t)b*1024*FD;
  size_t kbase = (size_t)b*NA*FD;

  f32x4 acc[4][4];
  #pragma unroll
  for (int i = 0; i < 4; ++i)
    #pragma unroll
    for (int j = 0; j < 4; ++j) acc[i][j] = (f32x4)0.f;

  for (int kc = 0; kc < 256; kc += 64) {
    #pragma unroll
    for (int i = 0; i < 4; ++i) {
      int r0 = (wid + 4*i) * 8;
      int lr = r0 + (lane >> 3);
      int lc = (lane & 7) ^ (lr & 7);
      gl2lds(qh + qbase + (size_t)(m0+lr)*FD + kc + lc*8, AsH + r0*64);
      gl2lds(ql + qbase + (size_t)(m0+lr)*FD + kc + lc*8, AsL + r0*64);
      int ar = a0 + lr; if (ar > NA-1) ar = NA-1;
      gl2lds(kh + kbase + (size_t)ar*FD + kc + lc*8, BsH + r0*64);
      gl2lds(kl + kbase + (size_t)ar*FD + kc + lc*8, BsL + r0*64);
    }
    __syncthreads();
    #pragma unroll
    for (int w = 0; w < 2; ++w) {
      int qq = w*4 + (lane >> 4);
      bf16x8 ah[4], al[4], bh[4], bl[4];
      #pragma unroll
      for (int i = 0; i < 4; ++i) {
        int ra = wr*64 + i*16 + (lane & 15);
        ah[i] = fld(AsH, ra, qq); al[i] = fld(AsL, ra, qq);
        int rb = wc*64 + i*16 + (lane & 15);
        bh[i] = fld(BsH, rb, qq); bl[i] = fld(BsL, rb, qq);
      }
      #pragma unroll
      for (int mt = 0; mt < 4; ++mt)
        #pragma unroll
        for (int nt = 0; nt < 4; ++nt)
          acc[mt][nt] = mfma3(ah[mt], al[mt], bh[nt], bl[nt], acc[mt][nt]);
    }
    __syncthreads();
  }

  #pragma unroll
  for (int mt = 0; mt < 4; ++mt) {
    int m = m0 + wr*64 + mt*16 + (lane >> 4)*4;
    #pragma unroll
    for (int nt = 0; nt < 4; ++nt) {
      int col = a0 + wc*64 + nt*16 + (lane & 15);
      #pragma unroll
      for (int r = 0; r < 4; ++r)
        logits[(size_t)(m+r)*LSTR + col] = acc[mt][nt][r];
    }
  }
}

// ================= softmax + exact top-64 + weighted v_area (on the fly) =================
__device__ __forceinline__ uint32_t f2key(float x) {
  uint32_t u = __float_as_uint(x);
  return (u & 0x80000000u) ? ~u : (u | 0x80000000u);
}

__global__ __launch_bounds__(256) void k_final(const float* __restrict__ logits,
    const float* __restrict__ Pv, const uint32_t* __restrict__ tab,
    float* __restrict__ outp, int b) {
  __shared__ float L[NA];
  __shared__ float red[4];
  __shared__ int   redi[4];
  __shared__ int   lst[192];
  __shared__ float lw[192];
  __shared__ int   shcnt;
  int t = threadIdx.x;
  int qrow = blockIdx.x;
  const float* row = logits + (size_t)qrow*LSTR;

  uint32_t keys[34];
  float vmax = -__builtin_inff();
  #pragma unroll
  for (int i = 0; i < 34; ++i) {
    int idx = t + i*256;
    float x = (idx < NA) ? row[idx] : -__builtin_inff();
    if (idx < NA) L[idx] = x;
    keys[i] = f2key(x);
    vmax = fmaxf(vmax, x);
  }
  #pragma unroll
  for (int off = 32; off >= 1; off >>= 1) vmax = fmaxf(vmax, __shfl_xor(vmax, off));
  if ((t & 63) == 0) red[t >> 6] = vmax;
  __syncthreads();
  float maxv = fmaxf(fmaxf(red[0], red[1]), fmaxf(red[2], red[3]));

  uint32_t lo = 0u, hi = 0xFFFFFFFFu;
  for (int it = 0; it < 32; ++it) {
    uint32_t mid = (uint32_t)((((uint64_t)lo + (uint64_t)hi) + 1ull) >> 1);
    int c = 0;
    #pragma unroll
    for (int i = 0; i < 34; ++i) c += (keys[i] >= mid) ? 1 : 0;
    #pragma unroll
    for (int off = 32; off >= 1; off >>= 1) c += __shfl_xor(c, off);
    if ((t & 63) == 0) redi[t >> 6] = c;
    __syncthreads();
    int ctot = redi[0] + redi[1] + redi[2] + redi[3];
    __syncthreads();
    if (ctot >= 64) lo = mid; else hi = mid - 1;
  }
  uint32_t thr = lo;

  if (t == 0) shcnt = 0;
  __syncthreads();
  #pragma unroll
  for (int i = 0; i < 34; ++i) {
    int idx = t + i*256;
    if (idx < NA && keys[i] >= thr) {
      int p = atomicAdd(&shcnt, 1);
      if (p < 192) lst[p] = idx;
    }
  }
  __syncthreads();
  int S = min(shcnt, 192);
  for (int i = t; i < S; i += 256) lw[i] = expf(L[lst[i]] - maxv);
  __syncthreads();
  float ssum = 0.f;
  if (t < 64) {
    for (int i = t; i < S; i += 64) ssum += lw[i];
    #pragma unroll
    for (int off = 32; off >= 1; off >>= 1) ssum += __shfl_xor(ssum, off);
    if (t == 0) red[0] = ssum;
  }
  __syncthreads();
  float inv = 1.0f / red[0];
  const float* Pvb = Pv + (size_t)b*PB;
  float accv = 0.f;
  for (int i = 0; i < S; ++i) {
    int a = lst[i];
    uint32_t tb = tab[a];
    int r1 = tb & 63, c1 = (tb>>6)&63, ah=(tb>>12)&3, aw=(tb>>14)&3;
    int r2 = r1+ah+1, c2 = c1+aw+1;
    float va = Pvb[(r2*33+c2)*FD + t] - Pvb[(r1*33+c2)*FD + t]
             - Pvb[(r2*33+c1)*FD + t] + Pvb[(r1*33+c1)*FD + t];
    accv += lw[i] * va;
  }
  outp[((size_t)b*1024 + qrow)*FD + t] = accv * inv;
}

// ================= launch =================
extern "C" void kernel_launch(void* const* d_in, const int* in_sizes, int n_in,
                              void* d_out, int out_size, void* d_ws, size_t ws_size,
                              hipStream_t stream) {
  const float* q  = (const float*)d_in[0];
  const float* k  = (const float*)d_in[1];
  const float* v  = (const float*)d_in[2];
  const float* eh = (const float*)d_in[3];
  const float* ew = (const float*)d_in[4];
  const float* W1 = (const float*)d_in[5];
  const float* b1 = (const float*)d_in[6];
  const float* W2 = (const float*)d_in[7];
  const float* b2 = (const float*)d_in[8];
  float* out = (float*)d_out;

  char* W = (char*)d_ws;
  auto alloc = [&](size_t bytes) -> char* {
    char* p = W; W += (bytes + 255) & ~(size_t)255; return p;
  };
  float* Pk    = (float*)alloc((size_t)8*PB*4);
  float* Pk2   = (float*)alloc((size_t)8*PB*4);
  float* Pv    = (float*)alloc((size_t)8*PB*4);
  ushort_t* qh = (ushort_t*)alloc((size_t)8*1024*FD*2);
  ushort_t* ql = (ushort_t*)alloc((size_t)8*1024*FD*2);
  ushort_t* w1h = (ushort_t*)alloc(131072*2);
  ushort_t* w1l = (ushort_t*)alloc(131072*2);
  ushort_t* w2h = (ushort_t*)alloc(65536*2);
  ushort_t* w2l = (ushort_t*)alloc(65536*2);
  float* bias9 = (float*)alloc(9*FD*4);
  uint32_t* tab = (uint32_t*)alloc(NA*4);
  ushort_t* hh = (ushort_t*)alloc((size_t)MT*FD*2);
  ushort_t* hl = (ushort_t*)alloc((size_t)MT*FD*2);
  ushort_t* kh = (ushort_t*)alloc((size_t)MT*FD*2);
  ushort_t* kl = (ushort_t*)alloc((size_t)MT*FD*2);
  float* logits = (float*)hh;   // overlay: h dead after k_l2

  k_rowsum<<<dim3(256), dim3(256), 0, stream>>>(k, v, Pk, Pk2, Pv);
  k_colsum<<<dim3(33, 8), dim3(256), 0, stream>>>(Pk, Pk2, Pv);
  k_tab<<<dim3(34), dim3(256), 0, stream>>>(tab);
  k_bias9<<<dim3(9), dim3(256), 0, stream>>>(eh, ew, W1, b1, bias9);
  k_decompq<<<dim3(1024), dim3(256), 0, stream>>>(q, qh, ql);
  k_decompw<<<dim3(768), dim3(256), 0, stream>>>(W1, W2, w1h, w1l, w2h, w2l);
  k_l1<<<dim3(541), dim3(512), 0, stream>>>(Pk, Pk2, tab, w1h, w1l, bias9, hh, hl);
  k_l2<<<dim3(541), dim3(512), 0, stream>>>(hh, hl, w2h, w2l, b2, kh, kl);
  for (int b = 0; b < 8; ++b) {
    k_logits<<<dim3(8, 68), dim3(256), 0, stream>>>(qh, ql, kh, kl, logits, b);
    k_final<<<dim3(1024), dim3(256), 0, stream>>>(logits, Pv, tab, out, b);
  }
}

// Round 3
// 760.148 us; speedup vs baseline: 2.2392x; 1.7011x over previous
//
#include <hip/hip_runtime.h>
#include <stdint.h>

#define FD   256
#define NA   8649
#define MT   69192          // 8*NA flattened rows
#define LSTR 8704
#define PB   (33*33*FD)

typedef unsigned short ushort_t;
typedef short bf16x8 __attribute__((ext_vector_type(8)));
typedef float f32x4  __attribute__((ext_vector_type(4)));

// ---------- bf16 helpers ----------
__device__ __forceinline__ unsigned short f2bf(float x) {
  unsigned int u = __float_as_uint(x);
  unsigned int r = (u + 0x7FFFu + ((u >> 16) & 1u)) >> 16;
  return (unsigned short)r;
}
__device__ __forceinline__ float bf2f(unsigned short h) {
  return __uint_as_float(((unsigned int)h) << 16);
}
__device__ __forceinline__ void dec2(float x, unsigned short& h, unsigned short& l) {
  h = f2bf(x);
  l = f2bf(x - bf2f(h));
}

// ---------- global->LDS direct (width 16), wave-uniform dst + lane*16 ----------
__device__ __forceinline__ void gl2lds(const void* g, void* l) {
  __builtin_amdgcn_global_load_lds(
      (const __attribute__((address_space(1))) void*)g,
      (__attribute__((address_space(3))) void*)l, 16, 0, 0);
}

// ---------- LDS fragment read: [128][32] bf16 rows, chunk-XOR swizzle ----------
__device__ __forceinline__ bf16x8 fldq(const ushort_t* plane, int row, int qq) {
  return *(const bf16x8*)(plane + row*32 + ((qq ^ (row & 3)) << 3));
}

__device__ __forceinline__ f32x4 mfma2(bf16x8 ah, bf16x8 bh, bf16x8 bl, f32x4 acc) {
  acc = __builtin_amdgcn_mfma_f32_16x16x32_bf16(ah, bl, acc, 0, 0, 0);
  acc = __builtin_amdgcn_mfma_f32_16x16x32_bf16(ah, bh, acc, 0, 0, 0);
  return acc;
}
__device__ __forceinline__ f32x4 mfma3(bf16x8 ah, bf16x8 al, bf16x8 bh, bf16x8 bl, f32x4 acc) {
  acc = __builtin_amdgcn_mfma_f32_16x16x32_bf16(al, bh, acc, 0, 0, 0);
  acc = __builtin_amdgcn_mfma_f32_16x16x32_bf16(ah, bl, acc, 0, 0, 0);
  acc = __builtin_amdgcn_mfma_f32_16x16x32_bf16(ah, bh, acc, 0, 0, 0);
  return acc;
}

// ================= integral images =================
__global__ __launch_bounds__(256) void k_rowsum(const float* __restrict__ kin,
    const float* __restrict__ vin, float* __restrict__ Pk,
    float* __restrict__ Pk2, float* __restrict__ Pv) {
  int b = blockIdx.x >> 5, i = blockIdx.x & 31;
  int f = threadIdx.x;
  const float* kr = kin + ((size_t)b*1024 + i*32)*FD + f;
  const float* vr = vin + ((size_t)b*1024 + i*32)*FD + f;
  float sk = 0.f, sk2 = 0.f, sv = 0.f;
  size_t base = (size_t)b*PB + (size_t)(i+1)*33*FD + f;
  #pragma unroll
  for (int j = 0; j < 32; ++j) {
    float kv = kr[j*FD], vv = vr[j*FD];
    sk += kv; sk2 += kv*kv; sv += vv;
    size_t p = base + (size_t)(j+1)*FD;
    Pk[p] = sk; Pk2[p] = sk2; Pv[p] = sv;
  }
}

__global__ __launch_bounds__(256) void k_colsum(float* __restrict__ Pk,
    float* __restrict__ Pk2, float* __restrict__ Pv) {
  int j = blockIdx.x, b = blockIdx.y, f = threadIdx.x;
  size_t base = (size_t)b*PB + f;
  if (j == 0) {
    for (int i = 0; i < 33; ++i) {
      size_t p = base + (size_t)i*33*FD;
      Pk[p] = 0.f; Pk2[p] = 0.f; Pv[p] = 0.f;
    }
  } else {
    size_t p0 = base + (size_t)j*FD;
    Pk[p0] = 0.f; Pk2[p0] = 0.f; Pv[p0] = 0.f;
    float ak = 0.f, ak2 = 0.f, av = 0.f;
    for (int i = 1; i <= 32; ++i) {
      size_t p = base + ((size_t)i*33 + j)*FD;
      ak  += Pk[p];  Pk[p]  = ak;
      ak2 += Pk2[p]; Pk2[p] = ak2;
      av  += Pv[p];  Pv[p]  = av;
    }
  }
}

// ================= area table =================
__global__ __launch_bounds__(256) void k_tab(uint32_t* __restrict__ tab) {
  int a = blockIdx.x*256 + threadIdx.x;
  if (a >= NA) return;
  const int offs[10] = {0,1024,2016,2976,3968,4929,5859,6819,7749,8649};
  int s = 0;
  #pragma unroll
  for (int i = 1; i < 9; ++i) s += (a >= offs[i]) ? 1 : 0;
  int ah = s/3, aw = s - ah*3;
  int idx = a - offs[s];
  int wc = 32 - aw;
  int r = idx / wc;
  int c = idx - r*wc;
  tab[a] = (uint32_t)(r | (c<<6) | (ah<<12) | (aw<<14));
}

// ================= fold size-embed into 9 bias vectors =================
__global__ __launch_bounds__(256) void k_bias9(const float* __restrict__ eh,
    const float* __restrict__ ew, const float* __restrict__ W1,
    const float* __restrict__ b1, float* __restrict__ bias9) {
  int s = blockIdx.x, c = threadIdx.x;
  int ah = s/3, aw = s - ah*3;
  float acc = b1[c];
  for (int j = 0; j < 128; ++j) acc += eh[ah*128 + j] * W1[(size_t)(512+j)*FD + c];
  for (int j = 0; j < 128; ++j) acc += ew[aw*128 + j] * W1[(size_t)(640+j)*FD + c];
  bias9[s*FD + c] = acc;
}

// ================= decompose q into hi/lo bf16 =================
__global__ __launch_bounds__(256) void k_decompq(const float* __restrict__ q,
    ushort_t* __restrict__ qh, ushort_t* __restrict__ ql) {
  int i = (blockIdx.x*256 + threadIdx.x) * 8;
  float4 v0 = *(const float4*)(q + i);
  float4 v1 = *(const float4*)(q + i + 4);
  float e[8] = {v0.x, v0.y, v0.z, v0.w, v1.x, v1.y, v1.z, v1.w};
  bf16x8 h8, l8;
  #pragma unroll
  for (int j = 0; j < 8; ++j) {
    unsigned short hu, lu; dec2(e[j], hu, lu);
    h8[j] = (short)hu; l8[j] = (short)lu;
  }
  *(bf16x8*)(qh + i) = h8;
  *(bf16x8*)(ql + i) = l8;
}

// ================= decompose+transpose W1, W2 -> [n][k] hi/lo =================
__global__ __launch_bounds__(256) void k_decompw(const float* __restrict__ W1,
    const float* __restrict__ W2, ushort_t* __restrict__ w1h, ushort_t* __restrict__ w1l,
    ushort_t* __restrict__ w2h, ushort_t* __restrict__ w2l) {
  int e = blockIdx.x*256 + threadIdx.x;
  float x; unsigned short hu, lu;
  if (e < 131072) {
    int n = e >> 9, kk = e & 511;
    x = W1[(size_t)kk*FD + n];
    dec2(x, hu, lu);
    w1h[e] = hu; w1l[e] = lu;
  } else {
    int e2 = e - 131072;
    int n = e2 >> 8, kk = e2 & 255;
    x = W2[(size_t)kk*FD + n];
    dec2(x, hu, lu);
    w2h[e2] = hu; w2l[e2] = lu;
  }
}

// ================= X features: mean|std -> bf16 [MT][512] =================
__global__ __launch_bounds__(256) void k_xfeat(const float* __restrict__ Pk,
    const float* __restrict__ Pk2, const uint32_t* __restrict__ tab,
    ushort_t* __restrict__ xh) {
  int t = threadIdx.x;
  int row0 = blockIdx.x * 16;
  for (int rr = 0; rr < 16; ++rr) {
    int gr = row0 + rr;
    if (gr >= MT) return;
    int bi = gr / NA;
    int a  = gr - bi*NA;
    uint32_t tb = tab[a];
    int r1 = tb & 63, c1 = (tb>>6)&63, ah=(tb>>12)&3, aw=(tb>>14)&3;
    int r2 = r1+ah+1, c2 = c1+aw+1;
    const float* PKb  = Pk  + (size_t)bi*PB + t;
    const float* PK2b = Pk2 + (size_t)bi*PB + t;
    int i11=(r1*33+c1)*FD, i12=(r1*33+c2)*FD, i21=(r2*33+c1)*FD, i22=(r2*33+c2)*FD;
    float s  = PKb[i22]  - PKb[i12]  - PKb[i21]  + PKb[i11];
    float s2 = PK2b[i22] - PK2b[i12] - PK2b[i21] + PK2b[i11];
    float inv = 1.0f/(float)((ah+1)*(aw+1));
    float mean = s * inv;
    float sd = sqrtf(fabsf(s2*inv - mean*mean) + 1e-6f);
    xh[(size_t)gr*512 + t]       = f2bf(mean);
    xh[(size_t)gr*512 + 256 + t] = f2bf(sd);
  }
}

// ================= l1: h = relu(X @ W1t + bias9) ; A 1-plane, B 2-plane =================
// BM=BN=128, BK=32, 256 thr / 4 waves (2x2), dbuf + issue-early staging
__global__ __launch_bounds__(256) void k_l1(
    const ushort_t* __restrict__ xh, const ushort_t* __restrict__ w1h,
    const ushort_t* __restrict__ w1l, const float* __restrict__ bias9g,
    const uint32_t* __restrict__ tab, ushort_t* __restrict__ hh) {
  __shared__ ushort_t S[2][12288];   // per buf: A[0:4096] BH[4096:8192] BL[8192:12288]
  int t = threadIdx.x, lane = t & 63, wid = t >> 6;
  int wr = wid >> 1, wc = wid & 1;
  int row0 = blockIdx.x * 128;
  int col0 = blockIdx.y * 128;

  auto stage = [&](int s, int kc) {
    #pragma unroll
    for (int i = 0; i < 2; ++i) {           // A: 1 plane, 512 chunks
      int g = i*4 + wid;                    // 0..7
      int r = g*16 + (lane >> 2);
      int q = lane & 3;
      int rr = row0 + r; if (rr > MT-1) rr = MT-1;
      gl2lds(xh + (size_t)rr*512 + kc + ((q ^ (r & 3)) << 3), &S[s][g*512]);
    }
    #pragma unroll
    for (int i = 0; i < 4; ++i) {           // B: 2 planes, 1024 chunks
      int g = i*4 + wid;                    // 0..15
      const ushort_t* src = (g < 8) ? w1h : w1l;
      int gg = g & 7;
      int r = gg*16 + (lane >> 2);
      int q = lane & 3;
      gl2lds(src + (size_t)(col0 + r)*512 + kc + ((q ^ (r & 3)) << 3), &S[s][4096 + g*512]);
    }
  };

  f32x4 acc[4][4];
  #pragma unroll
  for (int i = 0; i < 4; ++i)
    #pragma unroll
    for (int j = 0; j < 4; ++j) acc[i][j] = (f32x4)0.f;

  stage(0, 0);
  __syncthreads();
  int cur = 0;
  for (int step = 0; step < 16; ++step) {
    if (step < 15) stage(cur ^ 1, (step+1)*32);
    const ushort_t* SA  = &S[cur][0];
    const ushort_t* SBH = &S[cur][4096];
    const ushort_t* SBL = &S[cur][8192];
    int qq = lane >> 4;
    bf16x8 a_[4], bh_[4], bl_[4];
    #pragma unroll
    for (int i = 0; i < 4; ++i) {
      a_[i]  = fldq(SA,  wr*64 + i*16 + (lane & 15), qq);
      bh_[i] = fldq(SBH, wc*64 + i*16 + (lane & 15), qq);
      bl_[i] = fldq(SBL, wc*64 + i*16 + (lane & 15), qq);
    }
    #pragma unroll
    for (int mt = 0; mt < 4; ++mt)
      #pragma unroll
      for (int nt = 0; nt < 4; ++nt)
        acc[mt][nt] = mfma2(a_[mt], bh_[nt], bl_[nt], acc[mt][nt]);
    if (step < 15) { __syncthreads(); cur ^= 1; }
  }

  #pragma unroll
  for (int mt = 0; mt < 4; ++mt) {
    int lrowb = wr*64 + mt*16 + (lane >> 4)*4;
    #pragma unroll
    for (int r = 0; r < 4; ++r) {
      int grow = row0 + lrowb + r;
      if (grow < MT) {
        int a = grow % NA;
        uint32_t tb = tab[a];
        int seg = ((tb>>12)&3)*3 + ((tb>>14)&3);
        const float* bseg = bias9g + seg*FD;
        #pragma unroll
        for (int nt = 0; nt < 4; ++nt) {
          int col = col0 + wc*64 + nt*16 + (lane & 15);
          float hv = fmaxf(acc[mt][nt][r] + bseg[col], 0.f);
          hh[(size_t)grow*FD + col] = f2bf(hv);
        }
      }
    }
  }
}

// ================= l2: k_area = h @ W2t + b2 -> hi/lo =================
__global__ __launch_bounds__(256) void k_l2(
    const ushort_t* __restrict__ hh, const ushort_t* __restrict__ w2h,
    const ushort_t* __restrict__ w2l, const float* __restrict__ b2,
    ushort_t* __restrict__ kh, ushort_t* __restrict__ kl) {
  __shared__ ushort_t S[2][12288];
  int t = threadIdx.x, lane = t & 63, wid = t >> 6;
  int wr = wid >> 1, wc = wid & 1;
  int row0 = blockIdx.x * 128;
  int col0 = blockIdx.y * 128;

  auto stage = [&](int s, int kc) {
    #pragma unroll
    for (int i = 0; i < 2; ++i) {
      int g = i*4 + wid;
      int r = g*16 + (lane >> 2);
      int q = lane & 3;
      int rr = row0 + r; if (rr > MT-1) rr = MT-1;
      gl2lds(hh + (size_t)rr*FD + kc + ((q ^ (r & 3)) << 3), &S[s][g*512]);
    }
    #pragma unroll
    for (int i = 0; i < 4; ++i) {
      int g = i*4 + wid;
      const ushort_t* src = (g < 8) ? w2h : w2l;
      int gg = g & 7;
      int r = gg*16 + (lane >> 2);
      int q = lane & 3;
      gl2lds(src + (size_t)(col0 + r)*FD + kc + ((q ^ (r & 3)) << 3), &S[s][4096 + g*512]);
    }
  };

  f32x4 acc[4][4];
  #pragma unroll
  for (int i = 0; i < 4; ++i)
    #pragma unroll
    for (int j = 0; j < 4; ++j) acc[i][j] = (f32x4)0.f;

  stage(0, 0);
  __syncthreads();
  int cur = 0;
  for (int step = 0; step < 8; ++step) {
    if (step < 7) stage(cur ^ 1, (step+1)*32);
    const ushort_t* SA  = &S[cur][0];
    const ushort_t* SBH = &S[cur][4096];
    const ushort_t* SBL = &S[cur][8192];
    int qq = lane >> 4;
    bf16x8 a_[4], bh_[4], bl_[4];
    #pragma unroll
    for (int i = 0; i < 4; ++i) {
      a_[i]  = fldq(SA,  wr*64 + i*16 + (lane & 15), qq);
      bh_[i] = fldq(SBH, wc*64 + i*16 + (lane & 15), qq);
      bl_[i] = fldq(SBL, wc*64 + i*16 + (lane & 15), qq);
    }
    #pragma unroll
    for (int mt = 0; mt < 4; ++mt)
      #pragma unroll
      for (int nt = 0; nt < 4; ++nt)
        acc[mt][nt] = mfma2(a_[mt], bh_[nt], bl_[nt], acc[mt][nt]);
    if (step < 7) { __syncthreads(); cur ^= 1; }
  }

  #pragma unroll
  for (int mt = 0; mt < 4; ++mt) {
    int lrowb = wr*64 + mt*16 + (lane >> 4)*4;
    #pragma unroll
    for (int r = 0; r < 4; ++r) {
      int grow = row0 + lrowb + r;
      if (grow < MT) {
        #pragma unroll
        for (int nt = 0; nt < 4; ++nt) {
          int col = col0 + wc*64 + nt*16 + (lane & 15);
          float kv = acc[mt][nt][r] + b2[col];
          unsigned short hu, lu; dec2(kv, hu, lu);
          kh[(size_t)grow*FD + col] = hu;
          kl[(size_t)grow*FD + col] = lu;
        }
      }
    }
  }
}

// ================= logits: q @ k_area^T, 3-term =================
__global__ __launch_bounds__(256) void k_logits(
    const ushort_t* __restrict__ qh, const ushort_t* __restrict__ ql,
    const ushort_t* __restrict__ kh, const ushort_t* __restrict__ kl,
    float* __restrict__ logits, int b) {
  __shared__ ushort_t S[2][16384];  // AH[0:4096] AL[4096:8192] BH[8192:12288] BL[12288:16384]
  int t = threadIdx.x, lane = t & 63, wid = t >> 6;
  int wr = wid >> 1, wc = wid & 1;
  int m0 = blockIdx.x * 128;
  int a0 = blockIdx.y * 128;
  size_t qbase = (size_t)b*1024*FD;
  size_t kbase = (size_t)b*NA*FD;

  auto stage = [&](int s, int kc) {
    #pragma unroll
    for (int i = 0; i < 4; ++i) {           // A: qh/ql
      int g = i*4 + wid;                    // 0..15
      const ushort_t* src = (g < 8) ? qh : ql;
      int gg = g & 7;
      int r = gg*16 + (lane >> 2);
      int q = lane & 3;
      gl2lds(src + qbase + (size_t)(m0 + r)*FD + kc + ((q ^ (r & 3)) << 3), &S[s][g*512]);
    }
    #pragma unroll
    for (int i = 0; i < 4; ++i) {           // B: kh/kl
      int g = i*4 + wid;
      const ushort_t* src = (g < 8) ? kh : kl;
      int gg = g & 7;
      int r = gg*16 + (lane >> 2);
      int q = lane & 3;
      int ar = a0 + r; if (ar > NA-1) ar = NA-1;
      gl2lds(src + kbase + (size_t)ar*FD + kc + ((q ^ (r & 3)) << 3), &S[s][8192 + g*512]);
    }
  };

  f32x4 acc[4][4];
  #pragma unroll
  for (int i = 0; i < 4; ++i)
    #pragma unroll
    for (int j = 0; j < 4; ++j) acc[i][j] = (f32x4)0.f;

  stage(0, 0);
  __syncthreads();
  int cur = 0;
  for (int step = 0; step < 8; ++step) {
    if (step < 7) stage(cur ^ 1, (step+1)*32);
    const ushort_t* SAH = &S[cur][0];
    const ushort_t* SAL = &S[cur][4096];
    const ushort_t* SBH = &S[cur][8192];
    const ushort_t* SBL = &S[cur][12288];
    int qq = lane >> 4;
    bf16x8 ah_[4], al_[4], bh_[4], bl_[4];
    #pragma unroll
    for (int i = 0; i < 4; ++i) {
      int rr = i*16 + (lane & 15);
      ah_[i] = fldq(SAH, wr*64 + rr, qq);
      al_[i] = fldq(SAL, wr*64 + rr, qq);
      bh_[i] = fldq(SBH, wc*64 + rr, qq);
      bl_[i] = fldq(SBL, wc*64 + rr, qq);
    }
    #pragma unroll
    for (int mt = 0; mt < 4; ++mt)
      #pragma unroll
      for (int nt = 0; nt < 4; ++nt)
        acc[mt][nt] = mfma3(ah_[mt], al_[mt], bh_[nt], bl_[nt], acc[mt][nt]);
    if (step < 7) { __syncthreads(); cur ^= 1; }
  }

  #pragma unroll
  for (int mt = 0; mt < 4; ++mt) {
    int m = m0 + wr*64 + mt*16 + (lane >> 4)*4;
    #pragma unroll
    for (int nt = 0; nt < 4; ++nt) {
      int col = a0 + wc*64 + nt*16 + (lane & 15);
      #pragma unroll
      for (int r = 0; r < 4; ++r)
        logits[(size_t)(m+r)*LSTR + col] = acc[mt][nt][r];
    }
  }
}

// ================= softmax + exact top-64 + weighted v_area =================
__device__ __forceinline__ uint32_t f2key(float x) {
  uint32_t u = __float_as_uint(x);
  return (u & 0x80000000u) ? ~u : (u | 0x80000000u);
}

__global__ __launch_bounds__(256) void k_final(const float* __restrict__ logits,
    const float* __restrict__ Pv, const uint32_t* __restrict__ tab,
    float* __restrict__ outp, int b) {
  __shared__ float L[NA];
  __shared__ float red[4];
  __shared__ int   redi[4];
  __shared__ int   lst[192];
  __shared__ float lw[192];
  __shared__ int   shcnt;
  int t = threadIdx.x;
  int qrow = blockIdx.x;
  const float* row = logits + (size_t)qrow*LSTR;

  uint32_t keys[34];
  float vmax = -__builtin_inff();
  #pragma unroll
  for (int i = 0; i < 34; ++i) {
    int idx = t + i*256;
    float x = (idx < NA) ? row[idx] : -__builtin_inff();
    if (idx < NA) L[idx] = x;
    keys[i] = f2key(x);
    vmax = fmaxf(vmax, x);
  }
  #pragma unroll
  for (int off = 32; off >= 1; off >>= 1) vmax = fmaxf(vmax, __shfl_xor(vmax, off));
  if ((t & 63) == 0) red[t >> 6] = vmax;
  __syncthreads();
  float maxv = fmaxf(fmaxf(red[0], red[1]), fmaxf(red[2], red[3]));

  uint32_t lo = 0u, hi = 0xFFFFFFFFu;
  for (int it = 0; it < 32; ++it) {
    uint32_t mid = (uint32_t)((((uint64_t)lo + (uint64_t)hi) + 1ull) >> 1);
    int c = 0;
    #pragma unroll
    for (int i = 0; i < 34; ++i) c += (keys[i] >= mid) ? 1 : 0;
    #pragma unroll
    for (int off = 32; off >= 1; off >>= 1) c += __shfl_xor(c, off);
    if ((t & 63) == 0) redi[t >> 6] = c;
    __syncthreads();
    int ctot = redi[0] + redi[1] + redi[2] + redi[3];
    __syncthreads();
    if (ctot >= 64) lo = mid; else hi = mid - 1;
  }
  uint32_t thr = lo;

  if (t == 0) shcnt = 0;
  __syncthreads();
  #pragma unroll
  for (int i = 0; i < 34; ++i) {
    int idx = t + i*256;
    if (idx < NA && keys[i] >= thr) {
      int p = atomicAdd(&shcnt, 1);
      if (p < 192) lst[p] = idx;
    }
  }
  __syncthreads();
  int S = min(shcnt, 192);
  for (int i = t; i < S; i += 256) lw[i] = expf(L[lst[i]] - maxv);
  __syncthreads();
  float ssum = 0.f;
  if (t < 64) {
    for (int i = t; i < S; i += 64) ssum += lw[i];
    #pragma unroll
    for (int off = 32; off >= 1; off >>= 1) ssum += __shfl_xor(ssum, off);
    if (t == 0) red[0] = ssum;
  }
  __syncthreads();
  float inv = 1.0f / red[0];
  const float* Pvb = Pv + (size_t)b*PB;
  float accv = 0.f;
  for (int i = 0; i < S; ++i) {
    int a = lst[i];
    uint32_t tb = tab[a];
    int r1 = tb & 63, c1 = (tb>>6)&63, ah=(tb>>12)&3, aw=(tb>>14)&3;
    int r2 = r1+ah+1, c2 = c1+aw+1;
    float va = Pvb[(r2*33+c2)*FD + t] - Pvb[(r1*33+c2)*FD + t]
             - Pvb[(r2*33+c1)*FD + t] + Pvb[(r1*33+c1)*FD + t];
    accv += lw[i] * va;
  }
  outp[((size_t)b*1024 + qrow)*FD + t] = accv * inv;
}

// ================= launch =================
extern "C" void kernel_launch(void* const* d_in, const int* in_sizes, int n_in,
                              void* d_out, int out_size, void* d_ws, size_t ws_size,
                              hipStream_t stream) {
  const float* q  = (const float*)d_in[0];
  const float* k  = (const float*)d_in[1];
  const float* v  = (const float*)d_in[2];
  const float* eh = (const float*)d_in[3];
  const float* ew = (const float*)d_in[4];
  const float* W1 = (const float*)d_in[5];
  const float* b1 = (const float*)d_in[6];
  const float* W2 = (const float*)d_in[7];
  const float* b2 = (const float*)d_in[8];
  float* out = (float*)d_out;

  char* W = (char*)d_ws;
  auto alloc = [&](size_t bytes) -> char* {
    char* p = W; W += (bytes + 255) & ~(size_t)255; return p;
  };
  float*    Pv  = (float*)alloc((size_t)8*PB*4);
  ushort_t* qh  = (ushort_t*)alloc((size_t)8*1024*FD*2);
  ushort_t* ql  = (ushort_t*)alloc((size_t)8*1024*FD*2);
  ushort_t* w1h = (ushort_t*)alloc(131072*2);
  ushort_t* w1l = (ushort_t*)alloc(131072*2);
  ushort_t* w2h = (ushort_t*)alloc(65536*2);
  ushort_t* w2l = (ushort_t*)alloc(65536*2);
  float*    bias9 = (float*)alloc(9*FD*4);
  uint32_t* tab = (uint32_t*)alloc(NA*4);
  // R1: Pk|Pk2 (dead after k_xfeat) then hh overlay
  char* R1 = alloc((size_t)MT*FD*2);                 // 35.43 MB >= 2*8*PB*4 (27.9)
  float* Pk  = (float*)R1;
  float* Pk2 = (float*)(R1 + (size_t)8*PB*4);
  ushort_t* hh = (ushort_t*)R1;
  // R2: xh (dead after k_l1) then kh|kl ; logits in upper part
  char* R2 = alloc((size_t)MT*FD*2*2 + (size_t)1024*LSTR*4);   // 106.5 MB >= xh (70.85)
  ushort_t* xh = (ushort_t*)R2;
  ushort_t* kh = (ushort_t*)R2;
  ushort_t* kl = (ushort_t*)(R2 + (size_t)MT*FD*2);
  float* logits = (float*)(R2 + (size_t)MT*FD*2*2);

  k_rowsum<<<dim3(256), dim3(256), 0, stream>>>(k, v, Pk, Pk2, Pv);
  k_colsum<<<dim3(33, 8), dim3(256), 0, stream>>>(Pk, Pk2, Pv);
  k_tab<<<dim3(34), dim3(256), 0, stream>>>(tab);
  k_bias9<<<dim3(9), dim3(256), 0, stream>>>(eh, ew, W1, b1, bias9);
  k_decompq<<<dim3(1024), dim3(256), 0, stream>>>(q, qh, ql);
  k_decompw<<<dim3(768), dim3(256), 0, stream>>>(W1, W2, w1h, w1l, w2h, w2l);
  k_xfeat<<<dim3((MT+15)/16), dim3(256), 0, stream>>>(Pk, Pk2, tab, xh);
  k_l1<<<dim3(541, 2), dim3(256), 0, stream>>>(xh, w1h, w1l, bias9, tab, hh);
  k_l2<<<dim3(541, 2), dim3(256), 0, stream>>>(hh, w2h, w2l, b2, kh, kl);
  for (int b = 0; b < 8; ++b) {
    k_logits<<<dim3(8, 68), dim3(256), 0, stream>>>(qh, ql, kh, kl, logits, b);
    k_final<<<dim3(1024), dim3(256), 0, stream>>>(logits, Pv, tab, out, b);
  }
}

// Round 4
// 749.071 us; speedup vs baseline: 2.2723x; 1.0148x over previous
//
#include <hip/hip_runtime.h>
#include <stdint.h>

#define FD   256
#define NA   8649
#define MT   69192          // 8*NA flattened rows
#define LSTR 8704
#define PB   (33*33*FD)

typedef unsigned short ushort_t;
typedef short bf16x8 __attribute__((ext_vector_type(8)));
typedef float f32x4  __attribute__((ext_vector_type(4)));

// swizzle: slot = qq ^ SWZ(row). Within a 16-lane quarter (fixed qq) rows
// differ in bits 0..3; bits 2..3 select the 16B slot so each 4-bank group
// gets exactly 2 lanes (2-way = free, m136).
#define SWZ(r) (((r) >> 2) & 3)

// ---------- bf16 helpers ----------
__device__ __forceinline__ unsigned short f2bf(float x) {
  unsigned int u = __float_as_uint(x);
  unsigned int r = (u + 0x7FFFu + ((u >> 16) & 1u)) >> 16;
  return (unsigned short)r;
}
__device__ __forceinline__ float bf2f(unsigned short h) {
  return __uint_as_float(((unsigned int)h) << 16);
}
__device__ __forceinline__ void dec2(float x, unsigned short& h, unsigned short& l) {
  h = f2bf(x);
  l = f2bf(x - bf2f(h));
}

// ---------- global->LDS direct (width 16), wave-uniform dst + lane*16 ----------
__device__ __forceinline__ void gl2lds(const void* g, void* l) {
  __builtin_amdgcn_global_load_lds(
      (const __attribute__((address_space(1))) void*)g,
      (__attribute__((address_space(3))) void*)l, 16, 0, 0);
}

// ---------- LDS fragment read: [128][32] bf16 rows, chunk-XOR swizzle ----------
__device__ __forceinline__ bf16x8 fldq(const ushort_t* plane, int row, int qq) {
  return *(const bf16x8*)(plane + row*32 + ((qq ^ SWZ(row)) << 3));
}

__device__ __forceinline__ f32x4 mfma2(bf16x8 ah, bf16x8 bh, bf16x8 bl, f32x4 acc) {
  acc = __builtin_amdgcn_mfma_f32_16x16x32_bf16(ah, bl, acc, 0, 0, 0);
  acc = __builtin_amdgcn_mfma_f32_16x16x32_bf16(ah, bh, acc, 0, 0, 0);
  return acc;
}
__device__ __forceinline__ f32x4 mfma3(bf16x8 ah, bf16x8 al, bf16x8 bh, bf16x8 bl, f32x4 acc) {
  acc = __builtin_amdgcn_mfma_f32_16x16x32_bf16(al, bh, acc, 0, 0, 0);
  acc = __builtin_amdgcn_mfma_f32_16x16x32_bf16(ah, bl, acc, 0, 0, 0);
  acc = __builtin_amdgcn_mfma_f32_16x16x32_bf16(ah, bh, acc, 0, 0, 0);
  return acc;
}

// ================= integral images =================
__global__ __launch_bounds__(256) void k_rowsum(const float* __restrict__ kin,
    const float* __restrict__ vin, float* __restrict__ Pk,
    float* __restrict__ Pk2, float* __restrict__ Pv) {
  int b = blockIdx.x >> 5, i = blockIdx.x & 31;
  int f = threadIdx.x;
  const float* kr = kin + ((size_t)b*1024 + i*32)*FD + f;
  const float* vr = vin + ((size_t)b*1024 + i*32)*FD + f;
  float sk = 0.f, sk2 = 0.f, sv = 0.f;
  size_t base = (size_t)b*PB + (size_t)(i+1)*33*FD + f;
  #pragma unroll
  for (int j = 0; j < 32; ++j) {
    float kv = kr[j*FD], vv = vr[j*FD];
    sk += kv; sk2 += kv*kv; sv += vv;
    size_t p = base + (size_t)(j+1)*FD;
    Pk[p] = sk; Pk2[p] = sk2; Pv[p] = sv;
  }
}

__global__ __launch_bounds__(256) void k_colsum(float* __restrict__ Pk,
    float* __restrict__ Pk2, float* __restrict__ Pv) {
  int j = blockIdx.x, b = blockIdx.y, f = threadIdx.x;
  float* P = (blockIdx.z == 0) ? Pk : (blockIdx.z == 1) ? Pk2 : Pv;
  size_t base = (size_t)b*PB + f;
  if (j == 0) {
    for (int i = 0; i < 33; ++i) P[base + (size_t)i*33*FD] = 0.f;
  } else {
    P[base + (size_t)j*FD] = 0.f;
    float a = 0.f;
    for (int i = 1; i <= 32; ++i) {
      size_t p = base + ((size_t)i*33 + j)*FD;
      a += P[p]; P[p] = a;
    }
  }
}

// ================= area table =================
__global__ __launch_bounds__(256) void k_tab(uint32_t* __restrict__ tab) {
  int a = blockIdx.x*256 + threadIdx.x;
  if (a >= NA) return;
  const int offs[10] = {0,1024,2016,2976,3968,4929,5859,6819,7749,8649};
  int s = 0;
  #pragma unroll
  for (int i = 1; i < 9; ++i) s += (a >= offs[i]) ? 1 : 0;
  int ah = s/3, aw = s - ah*3;
  int idx = a - offs[s];
  int wc = 32 - aw;
  int r = idx / wc;
  int c = idx - r*wc;
  tab[a] = (uint32_t)(r | (c<<6) | (ah<<12) | (aw<<14));
}

// ================= fold size-embed into 9 bias vectors =================
__global__ __launch_bounds__(256) void k_bias9(const float* __restrict__ eh,
    const float* __restrict__ ew, const float* __restrict__ W1,
    const float* __restrict__ b1, float* __restrict__ bias9) {
  int s = blockIdx.x, c = threadIdx.x;
  int ah = s/3, aw = s - ah*3;
  float acc = b1[c];
  for (int j = 0; j < 128; ++j) acc += eh[ah*128 + j] * W1[(size_t)(512+j)*FD + c];
  for (int j = 0; j < 128; ++j) acc += ew[aw*128 + j] * W1[(size_t)(640+j)*FD + c];
  bias9[s*FD + c] = acc;
}

// ================= decompose q into hi/lo bf16 =================
__global__ __launch_bounds__(256) void k_decompq(const float* __restrict__ q,
    ushort_t* __restrict__ qh, ushort_t* __restrict__ ql) {
  int i = (blockIdx.x*256 + threadIdx.x) * 8;
  float4 v0 = *(const float4*)(q + i);
  float4 v1 = *(const float4*)(q + i + 4);
  float e[8] = {v0.x, v0.y, v0.z, v0.w, v1.x, v1.y, v1.z, v1.w};
  bf16x8 h8, l8;
  #pragma unroll
  for (int j = 0; j < 8; ++j) {
    unsigned short hu, lu; dec2(e[j], hu, lu);
    h8[j] = (short)hu; l8[j] = (short)lu;
  }
  *(bf16x8*)(qh + i) = h8;
  *(bf16x8*)(ql + i) = l8;
}

// ================= decompose+transpose W1, W2 -> [n][k] hi/lo =================
__global__ __launch_bounds__(256) void k_decompw(const float* __restrict__ W1,
    const float* __restrict__ W2, ushort_t* __restrict__ w1h, ushort_t* __restrict__ w1l,
    ushort_t* __restrict__ w2h, ushort_t* __restrict__ w2l) {
  int e = blockIdx.x*256 + threadIdx.x;
  float x; unsigned short hu, lu;
  if (e < 131072) {
    int n = e >> 9, kk = e & 511;
    x = W1[(size_t)kk*FD + n];
    dec2(x, hu, lu);
    w1h[e] = hu; w1l[e] = lu;
  } else {
    int e2 = e - 131072;
    int n = e2 >> 8, kk = e2 & 255;
    x = W2[(size_t)kk*FD + n];
    dec2(x, hu, lu);
    w2h[e2] = hu; w2l[e2] = lu;
  }
}

// ================= X features: mean|std -> bf16 [MT][512] =================
__global__ __launch_bounds__(256) void k_xfeat(const float* __restrict__ Pk,
    const float* __restrict__ Pk2, const uint32_t* __restrict__ tab,
    ushort_t* __restrict__ xh) {
  int t = threadIdx.x;
  int row0 = blockIdx.x * 16;
  for (int rr = 0; rr < 16; ++rr) {
    int gr = row0 + rr;
    if (gr >= MT) return;
    int bi = gr / NA;
    int a  = gr - bi*NA;
    uint32_t tb = tab[a];
    int r1 = tb & 63, c1 = (tb>>6)&63, ah=(tb>>12)&3, aw=(tb>>14)&3;
    int r2 = r1+ah+1, c2 = c1+aw+1;
    const float* PKb  = Pk  + (size_t)bi*PB + t;
    const float* PK2b = Pk2 + (size_t)bi*PB + t;
    int i11=(r1*33+c1)*FD, i12=(r1*33+c2)*FD, i21=(r2*33+c1)*FD, i22=(r2*33+c2)*FD;
    float s  = PKb[i22]  - PKb[i12]  - PKb[i21]  + PKb[i11];
    float s2 = PK2b[i22] - PK2b[i12] - PK2b[i21] + PK2b[i11];
    float inv = 1.0f/(float)((ah+1)*(aw+1));
    float mean = s * inv;
    float sd = sqrtf(fabsf(s2*inv - mean*mean) + 1e-6f);
    xh[(size_t)gr*512 + t]       = f2bf(mean);
    xh[(size_t)gr*512 + 256 + t] = f2bf(sd);
  }
}

// ================= l1: h = relu(X @ W1t + bias9) ; A 1-plane, B 2-plane =================
__global__ __launch_bounds__(256) void k_l1(
    const ushort_t* __restrict__ xh, const ushort_t* __restrict__ w1h,
    const ushort_t* __restrict__ w1l, const float* __restrict__ bias9g,
    const uint32_t* __restrict__ tab, ushort_t* __restrict__ hh) {
  __shared__ ushort_t S[2][12288];   // per buf: A[0:4096] BH[4096:8192] BL[8192:12288]
  int t = threadIdx.x, lane = t & 63, wid = t >> 6;
  int wr = wid >> 1, wc = wid & 1;
  int row0 = blockIdx.x * 128;
  int col0 = blockIdx.y * 128;

  auto stage = [&](int s, int kc) {
    #pragma unroll
    for (int i = 0; i < 2; ++i) {           // A: 1 plane
      int g = i*4 + wid;                    // 0..7
      int r = g*16 + (lane >> 2);
      int q = lane & 3;
      int rr = row0 + r; if (rr > MT-1) rr = MT-1;
      gl2lds(xh + (size_t)rr*512 + kc + ((q ^ SWZ(r)) << 3), &S[s][g*512]);
    }
    #pragma unroll
    for (int i = 0; i < 4; ++i) {           // B: 2 planes
      int g = i*4 + wid;                    // 0..15
      const ushort_t* src = (g < 8) ? w1h : w1l;
      int gg = g & 7;
      int r = gg*16 + (lane >> 2);
      int q = lane & 3;
      gl2lds(src + (size_t)(col0 + r)*512 + kc + ((q ^ SWZ(r)) << 3), &S[s][4096 + g*512]);
    }
  };

  f32x4 acc[4][4];
  #pragma unroll
  for (int i = 0; i < 4; ++i)
    #pragma unroll
    for (int j = 0; j < 4; ++j) acc[i][j] = (f32x4)0.f;

  stage(0, 0);
  __syncthreads();
  int cur = 0;
  for (int step = 0; step < 16; ++step) {
    if (step < 15) stage(cur ^ 1, (step+1)*32);
    const ushort_t* SA  = &S[cur][0];
    const ushort_t* SBH = &S[cur][4096];
    const ushort_t* SBL = &S[cur][8192];
    int qq = lane >> 4;
    bf16x8 a_[4], bh_[4], bl_[4];
    #pragma unroll
    for (int i = 0; i < 4; ++i) {
      a_[i]  = fldq(SA,  wr*64 + i*16 + (lane & 15), qq);
      bh_[i] = fldq(SBH, wc*64 + i*16 + (lane & 15), qq);
      bl_[i] = fldq(SBL, wc*64 + i*16 + (lane & 15), qq);
    }
    #pragma unroll
    for (int mt = 0; mt < 4; ++mt)
      #pragma unroll
      for (int nt = 0; nt < 4; ++nt)
        acc[mt][nt] = mfma2(a_[mt], bh_[nt], bl_[nt], acc[mt][nt]);
    if (step < 15) { __syncthreads(); cur ^= 1; }
  }

  #pragma unroll
  for (int mt = 0; mt < 4; ++mt) {
    int lrowb = wr*64 + mt*16 + (lane >> 4)*4;
    #pragma unroll
    for (int r = 0; r < 4; ++r) {
      int grow = row0 + lrowb + r;
      if (grow < MT) {
        int a = grow % NA;
        uint32_t tb = tab[a];
        int seg = ((tb>>12)&3)*3 + ((tb>>14)&3);
        const float* bseg = bias9g + seg*FD;
        #pragma unroll
        for (int nt = 0; nt < 4; ++nt) {
          int col = col0 + wc*64 + nt*16 + (lane & 15);
          float hv = fmaxf(acc[mt][nt][r] + bseg[col], 0.f);
          hh[(size_t)grow*FD + col] = f2bf(hv);
        }
      }
    }
  }
}

// ================= l2: k_area = h @ W2t + b2 -> hi/lo =================
__global__ __launch_bounds__(256) void k_l2(
    const ushort_t* __restrict__ hh, const ushort_t* __restrict__ w2h,
    const ushort_t* __restrict__ w2l, const float* __restrict__ b2,
    ushort_t* __restrict__ kh, ushort_t* __restrict__ kl) {
  __shared__ ushort_t S[2][12288];
  int t = threadIdx.x, lane = t & 63, wid = t >> 6;
  int wr = wid >> 1, wc = wid & 1;
  int row0 = blockIdx.x * 128;
  int col0 = blockIdx.y * 128;

  auto stage = [&](int s, int kc) {
    #pragma unroll
    for (int i = 0; i < 2; ++i) {
      int g = i*4 + wid;
      int r = g*16 + (lane >> 2);
      int q = lane & 3;
      int rr = row0 + r; if (rr > MT-1) rr = MT-1;
      gl2lds(hh + (size_t)rr*FD + kc + ((q ^ SWZ(r)) << 3), &S[s][g*512]);
    }
    #pragma unroll
    for (int i = 0; i < 4; ++i) {
      int g = i*4 + wid;
      const ushort_t* src = (g < 8) ? w2h : w2l;
      int gg = g & 7;
      int r = gg*16 + (lane >> 2);
      int q = lane & 3;
      gl2lds(src + (size_t)(col0 + r)*FD + kc + ((q ^ SWZ(r)) << 3), &S[s][4096 + g*512]);
    }
  };

  f32x4 acc[4][4];
  #pragma unroll
  for (int i = 0; i < 4; ++i)
    #pragma unroll
    for (int j = 0; j < 4; ++j) acc[i][j] = (f32x4)0.f;

  stage(0, 0);
  __syncthreads();
  int cur = 0;
  for (int step = 0; step < 8; ++step) {
    if (step < 7) stage(cur ^ 1, (step+1)*32);
    const ushort_t* SA  = &S[cur][0];
    const ushort_t* SBH = &S[cur][4096];
    const ushort_t* SBL = &S[cur][8192];
    int qq = lane >> 4;
    bf16x8 a_[4], bh_[4], bl_[4];
    #pragma unroll
    for (int i = 0; i < 4; ++i) {
      a_[i]  = fldq(SA,  wr*64 + i*16 + (lane & 15), qq);
      bh_[i] = fldq(SBH, wc*64 + i*16 + (lane & 15), qq);
      bl_[i] = fldq(SBL, wc*64 + i*16 + (lane & 15), qq);
    }
    #pragma unroll
    for (int mt = 0; mt < 4; ++mt)
      #pragma unroll
      for (int nt = 0; nt < 4; ++nt)
        acc[mt][nt] = mfma2(a_[mt], bh_[nt], bl_[nt], acc[mt][nt]);
    if (step < 7) { __syncthreads(); cur ^= 1; }
  }

  #pragma unroll
  for (int mt = 0; mt < 4; ++mt) {
    int lrowb = wr*64 + mt*16 + (lane >> 4)*4;
    #pragma unroll
    for (int r = 0; r < 4; ++r) {
      int grow = row0 + lrowb + r;
      if (grow < MT) {
        #pragma unroll
        for (int nt = 0; nt < 4; ++nt) {
          int col = col0 + wc*64 + nt*16 + (lane & 15);
          float kv = acc[mt][nt][r] + b2[col];
          unsigned short hu, lu; dec2(kv, hu, lu);
          kh[(size_t)grow*FD + col] = hu;
          kl[(size_t)grow*FD + col] = lu;
        }
      }
    }
  }
}

// ================= logits: q @ k_area^T, 3-term =================
__global__ __launch_bounds__(256) void k_logits(
    const ushort_t* __restrict__ qh, const ushort_t* __restrict__ ql,
    const ushort_t* __restrict__ kh, const ushort_t* __restrict__ kl,
    float* __restrict__ logits, int b) {
  __shared__ ushort_t S[2][16384];  // AH AL BH BL, 4096 each
  int t = threadIdx.x, lane = t & 63, wid = t >> 6;
  int wr = wid >> 1, wc = wid & 1;
  int m0 = blockIdx.x * 128;
  int a0 = blockIdx.y * 128;
  size_t qbase = (size_t)b*1024*FD;
  size_t kbase = (size_t)b*NA*FD;

  auto stage = [&](int s, int kc) {
    #pragma unroll
    for (int i = 0; i < 4; ++i) {           // A: qh/ql
      int g = i*4 + wid;                    // 0..15
      const ushort_t* src = (g < 8) ? qh : ql;
      int gg = g & 7;
      int r = gg*16 + (lane >> 2);
      int q = lane & 3;
      gl2lds(src + qbase + (size_t)(m0 + r)*FD + kc + ((q ^ SWZ(r)) << 3), &S[s][g*512]);
    }
    #pragma unroll
    for (int i = 0; i < 4; ++i) {           // B: kh/kl
      int g = i*4 + wid;
      const ushort_t* src = (g < 8) ? kh : kl;
      int gg = g & 7;
      int r = gg*16 + (lane >> 2);
      int q = lane & 3;
      int ar = a0 + r; if (ar > NA-1) ar = NA-1;
      gl2lds(src + kbase + (size_t)ar*FD + kc + ((q ^ SWZ(r)) << 3), &S[s][8192 + g*512]);
    }
  };

  f32x4 acc[4][4];
  #pragma unroll
  for (int i = 0; i < 4; ++i)
    #pragma unroll
    for (int j = 0; j < 4; ++j) acc[i][j] = (f32x4)0.f;

  stage(0, 0);
  __syncthreads();
  int cur = 0;
  for (int step = 0; step < 8; ++step) {
    if (step < 7) stage(cur ^ 1, (step+1)*32);
    const ushort_t* SAH = &S[cur][0];
    const ushort_t* SAL = &S[cur][4096];
    const ushort_t* SBH = &S[cur][8192];
    const ushort_t* SBL = &S[cur][12288];
    int qq = lane >> 4;
    bf16x8 ah_[4], al_[4], bh_[4], bl_[4];
    #pragma unroll
    for (int i = 0; i < 4; ++i) {
      int rr = i*16 + (lane & 15);
      ah_[i] = fldq(SAH, wr*64 + rr, qq);
      al_[i] = fldq(SAL, wr*64 + rr, qq);
      bh_[i] = fldq(SBH, wc*64 + rr, qq);
      bl_[i] = fldq(SBL, wc*64 + rr, qq);
    }
    #pragma unroll
    for (int mt = 0; mt < 4; ++mt)
      #pragma unroll
      for (int nt = 0; nt < 4; ++nt)
        acc[mt][nt] = mfma3(ah_[mt], al_[mt], bh_[nt], bl_[nt], acc[mt][nt]);
    if (step < 7) { __syncthreads(); cur ^= 1; }
  }

  #pragma unroll
  for (int mt = 0; mt < 4; ++mt) {
    int m = m0 + wr*64 + mt*16 + (lane >> 4)*4;
    #pragma unroll
    for (int nt = 0; nt < 4; ++nt) {
      int col = a0 + wc*64 + nt*16 + (lane & 15);
      #pragma unroll
      for (int r = 0; r < 4; ++r)
        logits[(size_t)(m+r)*LSTR + col] = acc[mt][nt][r];
    }
  }
}

// ================= softmax + exact top-64 (radix select) + weighted v_area =================
__device__ __forceinline__ uint32_t f2key(float x) {
  uint32_t u = __float_as_uint(x);
  return (u & 0x80000000u) ? ~u : (u | 0x80000000u);
}

__global__ __launch_bounds__(512) void k_final(const float* __restrict__ logits,
    const float* __restrict__ Pv, const uint32_t* __restrict__ tab,
    float* __restrict__ outp, int b) {
  __shared__ float L[8704];
  __shared__ int   hist[256];
  __shared__ float redf[8];
  __shared__ int   seli[2];      // selected byte, remaining rank
  __shared__ int   lst[192];
  __shared__ float lw[192];
  __shared__ float accvB[512];
  __shared__ int   shcnt;
  int t = threadIdx.x;
  int qrow = blockIdx.x;
  const float* row = logits + (size_t)qrow*LSTR;

  uint32_t keys[17];
  float vmax = -__builtin_inff();
  #pragma unroll
  for (int i = 0; i < 17; ++i) {
    int idx = t + i*512;
    float x = (idx < NA) ? row[idx] : -__builtin_inff();
    L[idx] = x;
    keys[i] = f2key(x);
    vmax = fmaxf(vmax, x);
  }
  #pragma unroll
  for (int off = 32; off >= 1; off >>= 1) vmax = fmaxf(vmax, __shfl_xor(vmax, off));
  if ((t & 63) == 0) redf[t >> 6] = vmax;

  // ---- radix-256 select: exact 64th-largest key in 4 rounds ----
  uint32_t prefix = 0; int need = 64;
  #pragma unroll
  for (int rd = 0; rd < 4; ++rd) {
    int shift = 24 - rd*8;
    uint32_t pmask = (rd == 0) ? 0u : (0xFFFFFFFFu << (shift + 8));
    if (t < 256) hist[t] = 0;
    __syncthreads();
    #pragma unroll
    for (int i = 0; i < 17; ++i)
      if ((keys[i] & pmask) == prefix)
        atomicAdd(&hist[(keys[i] >> shift) & 255], 1);
    __syncthreads();
    if (t < 64) {
      int b0 = t*4;
      int h0 = hist[b0], h1 = hist[b0+1], h2 = hist[b0+2], h3 = hist[b0+3];
      int s3 = h3, s2 = h2 + s3, s1 = h1 + s2, s0 = h0 + s1;
      int suf = s0;                          // becomes sum over lanes >= t
      #pragma unroll
      for (int d = 1; d < 64; d <<= 1) {
        int o = __shfl_down(suf, d);
        if (t + d < 64) suf += o;
      }
      int above = suf - s0;                  // cnt(byte >= 4t+4)
      int cg[5] = { above + s0, above + s1, above + s2, above + s3, above };
      #pragma unroll
      for (int j = 0; j < 4; ++j)
        if (cg[j] >= need && cg[j+1] < need) { seli[0] = b0 + j; seli[1] = need - cg[j+1]; }
    }
    __syncthreads();
    prefix |= ((uint32_t)seli[0]) << shift;
    need = seli[1];
    __syncthreads();
  }
  uint32_t thr = prefix;
  float maxv = redf[0];
  #pragma unroll
  for (int i = 1; i < 8; ++i) maxv = fmaxf(maxv, redf[i]);

  if (t == 0) shcnt = 0;
  __syncthreads();
  #pragma unroll
  for (int i = 0; i < 17; ++i) {
    int idx = t + i*512;
    if (idx < NA && keys[i] >= thr) {
      int p = atomicAdd(&shcnt, 1);
      if (p < 192) lst[p] = idx;
    }
  }
  __syncthreads();
  int S = min(shcnt, 192);
  for (int i = t; i < S; i += 512) lw[i] = expf(L[lst[i]] - maxv);
  __syncthreads();
  float ssum = 0.f;
  if (t < 64) {
    for (int i = t; i < S; i += 64) ssum += lw[i];
    #pragma unroll
    for (int off = 32; off >= 1; off >>= 1) ssum += __shfl_xor(ssum, off);
    if (t == 0) redf[0] = ssum;
  }
  __syncthreads();
  float inv = 1.0f / redf[0];
  int f = t & 255, half = t >> 8;
  const float* Pvb = Pv + (size_t)b*PB + f;
  float accv = 0.f;
  for (int i = half; i < S; i += 2) {
    int a = lst[i];
    uint32_t tb = tab[a];
    int r1 = tb & 63, c1 = (tb>>6)&63, ah=(tb>>12)&3, aw=(tb>>14)&3;
    int r2 = r1+ah+1, c2 = c1+aw+1;
    float va = Pvb[(r2*33+c2)*FD] - Pvb[(r1*33+c2)*FD]
             - Pvb[(r2*33+c1)*FD] + Pvb[(r1*33+c1)*FD];
    accv += lw[i] * va;
  }
  accvB[t] = accv;
  __syncthreads();
  if (t < 256)
    outp[((size_t)b*1024 + qrow)*FD + t] = (accvB[t] + accvB[t+256]) * inv;
}

// ================= launch =================
extern "C" void kernel_launch(void* const* d_in, const int* in_sizes, int n_in,
                              void* d_out, int out_size, void* d_ws, size_t ws_size,
                              hipStream_t stream) {
  const float* q  = (const float*)d_in[0];
  const float* k  = (const float*)d_in[1];
  const float* v  = (const float*)d_in[2];
  const float* eh = (const float*)d_in[3];
  const float* ew = (const float*)d_in[4];
  const float* W1 = (const float*)d_in[5];
  const float* b1 = (const float*)d_in[6];
  const float* W2 = (const float*)d_in[7];
  const float* b2 = (const float*)d_in[8];
  float* out = (float*)d_out;

  char* W = (char*)d_ws;
  auto alloc = [&](size_t bytes) -> char* {
    char* p = W; W += (bytes + 255) & ~(size_t)255; return p;
  };
  float*    Pv  = (float*)alloc((size_t)8*PB*4);
  ushort_t* qh  = (ushort_t*)alloc((size_t)8*1024*FD*2);
  ushort_t* ql  = (ushort_t*)alloc((size_t)8*1024*FD*2);
  ushort_t* w1h = (ushort_t*)alloc(131072*2);
  ushort_t* w1l = (ushort_t*)alloc(131072*2);
  ushort_t* w2h = (ushort_t*)alloc(65536*2);
  ushort_t* w2l = (ushort_t*)alloc(65536*2);
  float*    bias9 = (float*)alloc(9*FD*4);
  uint32_t* tab = (uint32_t*)alloc(NA*4);
  char* R1 = alloc((size_t)MT*FD*2);                 // Pk|Pk2 then hh overlay
  float* Pk  = (float*)R1;
  float* Pk2 = (float*)(R1 + (size_t)8*PB*4);
  ushort_t* hh = (ushort_t*)R1;
  char* R2 = alloc((size_t)MT*FD*2*2 + (size_t)1024*LSTR*4);   // xh then kh|kl + logits
  ushort_t* xh = (ushort_t*)R2;
  ushort_t* kh = (ushort_t*)R2;
  ushort_t* kl = (ushort_t*)(R2 + (size_t)MT*FD*2);
  float* logits = (float*)(R2 + (size_t)MT*FD*2*2);

  k_rowsum<<<dim3(256), dim3(256), 0, stream>>>(k, v, Pk, Pk2, Pv);
  k_colsum<<<dim3(33, 8, 3), dim3(256), 0, stream>>>(Pk, Pk2, Pv);
  k_tab<<<dim3(34), dim3(256), 0, stream>>>(tab);
  k_bias9<<<dim3(9), dim3(256), 0, stream>>>(eh, ew, W1, b1, bias9);
  k_decompq<<<dim3(1024), dim3(256), 0, stream>>>(q, qh, ql);
  k_decompw<<<dim3(768), dim3(256), 0, stream>>>(W1, W2, w1h, w1l, w2h, w2l);
  k_xfeat<<<dim3((MT+15)/16), dim3(256), 0, stream>>>(Pk, Pk2, tab, xh);
  k_l1<<<dim3(541, 2), dim3(256), 0, stream>>>(xh, w1h, w1l, bias9, tab, hh);
  k_l2<<<dim3(541, 2), dim3(256), 0, stream>>>(hh, w2h, w2l, b2, kh, kl);
  for (int b = 0; b < 8; ++b) {
    k_logits<<<dim3(8, 68), dim3(256), 0, stream>>>(qh, ql, kh, kl, logits, b);
    k_final<<<dim3(1024), dim3(512), 0, stream>>>(logits, Pv, tab, out, b);
  }
}